// Round 4
// baseline (887.224 us; speedup 1.0000x reference)
//
#include <hip/hip_runtime.h>

// N=100000 nodes, D=64, P=Q=32, E=3200000 edges.
// Aggregation via deterministic radix partition by dst bucket (R=128 nodes),
// then per-bucket LDS accumulation with 8-deep unrolled gather (MLP for
// latency hiding). No global atomics anywhere.

#define RLOG 7
#define RNODES 128          // nodes per bucket
#define NBLK 160            // partition blocks

__device__ __forceinline__ float softplus_f(float x) {
    return fmaxf(x, 0.0f) + log1pf(expf(-fabsf(x)));
}

__device__ __forceinline__ float bcastf(float v, int k) {
    return __uint_as_float(__builtin_amdgcn_readlane(__float_as_uint(v), k));
}

// ---- 1. per-block bucket histogram: cnt[b*NBLK + blk]
__global__ __launch_bounds__(1024) void bin_count(const int* __restrict__ edst,
                                                  int* __restrict__ cnt,
                                                  int E, int B) {
    __shared__ int lcnt[1024];
    int tid = threadIdx.x, blk = blockIdx.x;
    for (int b = tid; b < B; b += 1024) lcnt[b] = 0;
    __syncthreads();
    int chunk = (E + NBLK - 1) / NBLK;
    int start = blk * chunk;
    int end = min(E, start + chunk);
    for (int i = start + tid; i < end; i += 1024)
        atomicAdd(&lcnt[edst[i] >> RLOG], 1);
    __syncthreads();
    for (int b = tid; b < B; b += 1024) cnt[b * NBLK + blk] = lcnt[b];
}

// ---- 2a. per-block partial sums (1024 elems/block)
__global__ __launch_bounds__(1024) void scan_reduce(const int* __restrict__ cnt,
                                                    int* __restrict__ bsum, int M) {
    int idx = blockIdx.x * 1024 + threadIdx.x;
    int v = (idx < M) ? cnt[idx] : 0;
    #pragma unroll
    for (int off = 32; off; off >>= 1) v += __shfl_xor(v, off);
    __shared__ int wtot[16];
    int lane = threadIdx.x & 63, wave = threadIdx.x >> 6;
    if (lane == 0) wtot[wave] = v;
    __syncthreads();
    if (threadIdx.x == 0) {
        int s = 0;
        #pragma unroll
        for (int i = 0; i < 16; ++i) s += wtot[i];
        bsum[blockIdx.x] = s;
    }
}

// ---- 2b. exclusive scan of block sums (nb <= 128)
__global__ void scan_top(int* __restrict__ bsum, int nb) {
    int t = threadIdx.x;
    int v = (t < nb) ? bsum[t] : 0;
    int lane = t & 63, wave = t >> 6;
    int incl = v;
    #pragma unroll
    for (int off = 1; off < 64; off <<= 1) {
        int w = __shfl_up(incl, off);
        if (lane >= off) incl += w;
    }
    __shared__ int wt[2];
    if (lane == 63) wt[wave] = incl;
    __syncthreads();
    int excl = incl - v + ((wave == 1) ? wt[0] : 0);
    if (t < nb) bsum[t] = excl;
}

// ---- 2c. final exclusive scan -> offs
__global__ __launch_bounds__(1024) void scan_final(const int* __restrict__ cnt,
                                                   const int* __restrict__ bsum,
                                                   int* __restrict__ offs, int M) {
    int t = threadIdx.x;
    int idx = blockIdx.x * 1024 + t;
    int lane = t & 63, wave = t >> 6;
    int v = (idx < M) ? cnt[idx] : 0;
    int incl = v;
    #pragma unroll
    for (int off = 1; off < 64; off <<= 1) {
        int w = __shfl_up(incl, off);
        if (lane >= off) incl += w;
    }
    __shared__ int wtot[16];
    if (lane == 63) wtot[wave] = incl;
    __syncthreads();
    int woff = 0;
    for (int i = 0; i < wave; ++i) woff += wtot[i];
    if (idx < M) offs[idx] = bsum[blockIdx.x] + woff + incl - v;
}

// ---- 3. scatter packed entries using LDS cursors (no global atomics)
__global__ __launch_bounds__(1024) void bin_scatter(const int* __restrict__ esrc,
                                                    const int* __restrict__ edst,
                                                    const int* __restrict__ offs,
                                                    int* __restrict__ binned,
                                                    int E, int B) {
    __shared__ int lcur[1024];
    int tid = threadIdx.x, blk = blockIdx.x;
    for (int b = tid; b < B; b += 1024) lcur[b] = offs[b * NBLK + blk];
    __syncthreads();
    int chunk = (E + NBLK - 1) / NBLK;
    int start = blk * chunk;
    int end = min(E, start + chunk);
    for (int i = start + tid; i < end; i += 1024) {
        int d = edst[i];
        int s = esrc[i];
        int b = d >> RLOG;
        int pos = atomicAdd(&lcur[b], 1);
        binned[pos] = ((d & (RNODES - 1)) << 17) | s;
    }
}

// ---- 4. per-bucket aggregation in LDS, 8-deep unrolled gather
#define UNR 8
__global__ __launch_bounds__(512) void bucket_agg(const float* __restrict__ intensity,
                                                  const int* __restrict__ binned,
                                                  const int* __restrict__ offs,
                                                  float* __restrict__ nbr_mean,
                                                  int E, int N, int B) {
    __shared__ float acc[RNODES * 32];
    __shared__ int scnt[RNODES];
    int tid = threadIdx.x;
    int bucket = blockIdx.x;
    for (int i = tid; i < RNODES * 32; i += 512) acc[i] = 0.0f;
    for (int i = tid; i < RNODES; i += 512) scnt[i] = 0;
    __syncthreads();

    int start = offs[bucket * NBLK];
    int end = (bucket + 1 < B) ? offs[(bucket + 1) * NBLK] : E;

    int g = tid >> 5;          // 16 groups of 32 lanes
    int f = tid & 31;          // feature index

    int i = start + g;
    // main loop: 8 edges per group per iteration -> 8+ outstanding VMEM ops
    for (; i + 16 * (UNR - 1) < end; i += 16 * UNR) {
        int e[UNR];
        float v[UNR];
        #pragma unroll
        for (int uu = 0; uu < UNR; ++uu) e[uu] = binned[i + 16 * uu];
        #pragma unroll
        for (int uu = 0; uu < UNR; ++uu)
            v[uu] = intensity[(size_t)(e[uu] & 131071) * 32 + f];
        #pragma unroll
        for (int uu = 0; uu < UNR; ++uu) {
            atomicAdd(&acc[(e[uu] >> 17) * 32 + f], v[uu]);
            if (f == 0) atomicAdd(&scnt[e[uu] >> 17], 1);
        }
    }
    // tail
    for (; i < end; i += 16) {
        int e = binned[i];
        float v = intensity[(size_t)(e & 131071) * 32 + f];
        atomicAdd(&acc[(e >> 17) * 32 + f], v);
        if (f == 0) atomicAdd(&scnt[e >> 17], 1);
    }
    __syncthreads();

    for (int idx = tid; idx < RNODES * 32; idx += 512) {
        int dl = idx >> 5;
        int node = bucket * RNODES + dl;
        if (node < N) {
            float inv = 1.0f / (float)max(scnt[dl], 1);
            nbr_mean[(size_t)node * 32 + (idx & 31)] = acc[idx] * inv;
        }
    }
}

// ---- 5. fused node kernel: weights in registers, readlane broadcast
__global__ __launch_bounds__(256, 2) void node_kernel(
    const float* __restrict__ u, const float* __restrict__ intensity,
    const float* __restrict__ nbr_mean,
    const float* __restrict__ Wf, const float* __restrict__ bf,
    const float* __restrict__ Wg, const float* __restrict__ bg,
    const float* __restrict__ Wz, const float* __restrict__ bz,
    const float* __restrict__ WA, const float* __restrict__ bA,
    float* __restrict__ out, int N) {
    __shared__ float sWf[64 * 65];
    __shared__ float sWg[64 * 65];
    __shared__ float sW3[64 * 65];
    int tid = threadIdx.x;
    for (int idx = tid; idx < 4096; idx += 256) {
        int i = idx >> 6, k = idx & 63;
        sWf[i * 65 + k] = Wf[idx];
        sWg[i * 65 + k] = Wg[idx];
        sW3[i * 65 + k] = (i < 32) ? Wz[i * 64 + k] : WA[(i - 32) * 64 + k];
    }
    __syncthreads();

    int lane = tid & 63;
    int wave = tid >> 6;

    float wf[64], wg[64], w3[64];
    #pragma unroll
    for (int k = 0; k < 64; ++k) {
        wf[k] = sWf[lane * 65 + k];
        wg[k] = sWg[lane * 65 + k];
        w3[k] = sW3[lane * 65 + k];
    }
    float fb = bf[lane];
    float gb = bg[lane];
    float zb = (lane < 32) ? bz[lane] : bA[lane - 32];

    int gwave = blockIdx.x * 4 + wave;
    int wstride = gridDim.x * 4;
    for (int n = gwave; n < N; n += wstride) {
        float uval = u[(size_t)n * 64 + lane];
        float xval = (lane < 32) ? intensity[(size_t)n * 32 + lane]
                                 : nbr_mean[(size_t)n * 32 + (lane - 32)];
        float fA = fb, gA = gb, zA = zb;
        #pragma unroll
        for (int k = 0; k < 64; ++k) {
            float uk = bcastf(uval, k);
            float xk = bcastf(xval, k);
            float in3 = (lane < 32) ? uk : xk;
            fA = fmaf(wf[k], uk, fA);
            gA = fmaf(wg[k], uk, gA);
            zA = fmaf(w3[k], in3, zA);
        }
        float Fu = softplus_f(fA);
        float Gu = softplus_f(gA);
        float zv = (lane < 32) ? tanhf(zA) : fmaxf(zA, 0.0f);
        float du = -Fu * uval + Gu * zv;

        float a = (lane < 32) ? du * uval : 0.0f;
        float b = (lane < 32) ? uval * uval : 0.0f;
        #pragma unroll
        for (int off = 32; off; off >>= 1) {
            a += __shfl_xor(a, off);
            b += __shfl_xor(b, off);
        }
        out[(size_t)n * 64 + lane] = (lane < 32) ? (du - (a / b) * uval) : du;
    }
}

extern "C" void kernel_launch(void* const* d_in, const int* in_sizes, int n_in,
                              void* d_out, int out_size, void* d_ws, size_t ws_size,
                              hipStream_t stream) {
    const float* u         = (const float*)d_in[0];
    const float* intensity = (const float*)d_in[1];
    const int*   esrc      = (const int*)d_in[2];
    const int*   edst      = (const int*)d_in[3];
    const float* Wf        = (const float*)d_in[4];
    const float* bf        = (const float*)d_in[5];
    const float* Wg        = (const float*)d_in[6];
    const float* bg        = (const float*)d_in[7];
    const float* Wz        = (const float*)d_in[8];
    const float* bz        = (const float*)d_in[9];
    const float* WA        = (const float*)d_in[10];
    const float* bA        = (const float*)d_in[11];

    int N = in_sizes[0] / 64;
    int E = in_sizes[2];
    int B = (N + RNODES - 1) / RNODES;          // 782
    int M = B * NBLK;                            // 125120
    int nb = (M + 1023) / 1024;                  // 123 (<=128)

    int* cnt    = (int*)d_ws;                    // M
    int* offs   = cnt + M;                       // M
    int* bsum   = offs + M;                      // 128
    int* binned = bsum + 128;                    // E
    float* nbr_mean = (float*)(binned + E);      // N*32

    bin_count<<<NBLK, 1024, 0, stream>>>(edst, cnt, E, B);
    scan_reduce<<<nb, 1024, 0, stream>>>(cnt, bsum, M);
    scan_top<<<1, 128, 0, stream>>>(bsum, nb);
    scan_final<<<nb, 1024, 0, stream>>>(cnt, bsum, offs, M);
    bin_scatter<<<NBLK, 1024, 0, stream>>>(esrc, edst, offs, binned, E, B);
    bucket_agg<<<B, 512, 0, stream>>>(intensity, binned, offs, nbr_mean, E, N, B);
    node_kernel<<<1024, 256, 0, stream>>>(u, intensity, nbr_mean, Wf, bf, Wg, bg,
                                          Wz, bz, WA, bA, (float*)d_out, N);
}

// Round 5
// 272.903 us; speedup vs baseline: 3.2511x; 3.2511x over previous
//
#include <hip/hip_runtime.h>

// N=100000 nodes, D=64, P=Q=32, E=3200000 edges.
// Pipeline: bucket partition (radix by dst>>7, write-local) -> in-place
// node-sort per bucket (LDS staged) -> per-node CSR gather (high TLP,
// no LDS) -> fused node kernel. No global atomics anywhere.

#define RLOG 7
#define RNODES 128          // nodes per bucket
#define NBLK 160            // partition blocks
#define CAP 6144            // max edges per bucket staged in LDS (lambda=4092, 32 sigma)

__device__ __forceinline__ float softplus_f(float x) {
    return fmaxf(x, 0.0f) + log1pf(expf(-fabsf(x)));
}

__device__ __forceinline__ float bcastf(float v, int k) {
    return __uint_as_float(__builtin_amdgcn_readlane(__float_as_uint(v), k));
}

// ---- 1. per-block bucket histogram: cnt[b*NBLK + blk]
__global__ __launch_bounds__(1024) void bin_count(const int* __restrict__ edst,
                                                  int* __restrict__ cnt,
                                                  int E, int B) {
    __shared__ int lcnt[1024];
    int tid = threadIdx.x, blk = blockIdx.x;
    for (int b = tid; b < B; b += 1024) lcnt[b] = 0;
    __syncthreads();
    int chunk = (E + NBLK - 1) / NBLK;
    int start = blk * chunk;
    int end = min(E, start + chunk);
    for (int i = start + tid; i < end; i += 1024)
        atomicAdd(&lcnt[edst[i] >> RLOG], 1);
    __syncthreads();
    for (int b = tid; b < B; b += 1024) cnt[b * NBLK + blk] = lcnt[b];
}

// ---- 2a. per-block partial sums
__global__ __launch_bounds__(1024) void scan_reduce(const int* __restrict__ cnt,
                                                    int* __restrict__ bsum, int M) {
    int idx = blockIdx.x * 1024 + threadIdx.x;
    int v = (idx < M) ? cnt[idx] : 0;
    #pragma unroll
    for (int off = 32; off; off >>= 1) v += __shfl_xor(v, off);
    __shared__ int wtot[16];
    int lane = threadIdx.x & 63, wave = threadIdx.x >> 6;
    if (lane == 0) wtot[wave] = v;
    __syncthreads();
    if (threadIdx.x == 0) {
        int s = 0;
        #pragma unroll
        for (int i = 0; i < 16; ++i) s += wtot[i];
        bsum[blockIdx.x] = s;
    }
}

// ---- 2b. exclusive scan of block sums (nb <= 128)
__global__ void scan_top(int* __restrict__ bsum, int nb) {
    int t = threadIdx.x;
    int v = (t < nb) ? bsum[t] : 0;
    int lane = t & 63, wave = t >> 6;
    int incl = v;
    #pragma unroll
    for (int off = 1; off < 64; off <<= 1) {
        int w = __shfl_up(incl, off);
        if (lane >= off) incl += w;
    }
    __shared__ int wt[2];
    if (lane == 63) wt[wave] = incl;
    __syncthreads();
    int excl = incl - v + ((wave == 1) ? wt[0] : 0);
    if (t < nb) bsum[t] = excl;
}

// ---- 2c. final exclusive scan -> offs
__global__ __launch_bounds__(1024) void scan_final(const int* __restrict__ cnt,
                                                   const int* __restrict__ bsum,
                                                   int* __restrict__ offs, int M) {
    int t = threadIdx.x;
    int idx = blockIdx.x * 1024 + t;
    int lane = t & 63, wave = t >> 6;
    int v = (idx < M) ? cnt[idx] : 0;
    int incl = v;
    #pragma unroll
    for (int off = 1; off < 64; off <<= 1) {
        int w = __shfl_up(incl, off);
        if (lane >= off) incl += w;
    }
    __shared__ int wtot[16];
    if (lane == 63) wtot[wave] = incl;
    __syncthreads();
    int woff = 0;
    for (int i = 0; i < wave; ++i) woff += wtot[i];
    if (idx < M) offs[idx] = bsum[blockIdx.x] + woff + incl - v;
}

// ---- 3. scatter packed entries using LDS cursors (no global atomics)
__global__ __launch_bounds__(1024) void bin_scatter(const int* __restrict__ esrc,
                                                    const int* __restrict__ edst,
                                                    const int* __restrict__ offs,
                                                    int* __restrict__ binned,
                                                    int E, int B) {
    __shared__ int lcur[1024];
    int tid = threadIdx.x, blk = blockIdx.x;
    for (int b = tid; b < B; b += 1024) lcur[b] = offs[b * NBLK + blk];
    __syncthreads();
    int chunk = (E + NBLK - 1) / NBLK;
    int start = blk * chunk;
    int end = min(E, start + chunk);
    for (int i = start + tid; i < end; i += 1024) {
        int d = edst[i];
        int s = esrc[i];
        int b = d >> RLOG;
        int pos = atomicAdd(&lcur[b], 1);
        binned[pos] = ((d & (RNODES - 1)) << 17) | s;
    }
}

// ---- 4. in-place node sort within each bucket (LDS staged)
__global__ __launch_bounds__(256) void node_sort(int* __restrict__ binned,
                                                 const int* __restrict__ offs,
                                                 int* __restrict__ nodestart,
                                                 int* __restrict__ degarr,
                                                 int E, int N, int B) {
    __shared__ int sl[CAP];
    __shared__ int c128[RNODES];
    __shared__ int pos[RNODES];
    int tid = threadIdx.x;
    int b = blockIdx.x;
    int start = offs[b * NBLK];
    int end = (b + 1 < B) ? offs[(b + 1) * NBLK] : E;
    int m = min(end - start, CAP);

    for (int i = tid; i < m; i += 256) sl[i] = binned[start + i];
    if (tid < RNODES) c128[tid] = 0;
    __syncthreads();
    for (int i = tid; i < m; i += 256) atomicAdd(&c128[sl[i] >> 17], 1);
    __syncthreads();

    // Hillis-Steele inclusive scan over 128 counts (threads 0..127)
    int x = 0, incl = 0;
    if (tid < RNODES) { x = c128[tid]; incl = x; }
    #pragma unroll
    for (int off = 1; off < RNODES; off <<= 1) {
        int y = 0;
        if (tid < RNODES && tid >= off) y = c128[tid - off];
        __syncthreads();
        if (tid < RNODES) { incl += y; c128[tid] = incl; }
        __syncthreads();
    }
    if (tid < RNODES) {
        int excl = incl - x;
        pos[tid] = excl;
        int node = b * RNODES + tid;
        if (node < N) {
            nodestart[node] = start + excl;
            degarr[node] = x;
        }
    }
    __syncthreads();
    for (int i = tid; i < m; i += 256) {
        int e = sl[i];
        int p = atomicAdd(&pos[e >> 17], 1);
        binned[start + p] = e & 131071;   // store src only, node-sorted
    }
}

// ---- 5. gather: one wave per node, 8 groups x float4, unroll 2
__global__ __launch_bounds__(256) void gather_kernel(
    const float* __restrict__ intensity, const int* __restrict__ binned,
    const int* __restrict__ nodestart, const int* __restrict__ degarr,
    float* __restrict__ nbr_mean, int N) {
    int lane = threadIdx.x & 63;
    int wave = threadIdx.x >> 6;
    int gid = lane >> 3;       // 8 groups of 8 lanes
    int fl = lane & 7;         // float4 index within the 32-float row
    int gwave = blockIdx.x * 4 + wave;
    int wstride = gridDim.x * 4;
    for (int n = gwave; n < N; n += wstride) {
        int st = nodestart[n];
        int dg = degarr[n];
        float4 a = make_float4(0.f, 0.f, 0.f, 0.f);
        int j = gid;
        for (; j + 8 < dg; j += 16) {
            int s0 = binned[st + j];
            int s1 = binned[st + j + 8];
            float4 v0 = ((const float4*)intensity)[(size_t)s0 * 8 + fl];
            float4 v1 = ((const float4*)intensity)[(size_t)s1 * 8 + fl];
            a.x += v0.x + v1.x; a.y += v0.y + v1.y;
            a.z += v0.z + v1.z; a.w += v0.w + v1.w;
        }
        if (j < dg) {
            int s0 = binned[st + j];
            float4 v0 = ((const float4*)intensity)[(size_t)s0 * 8 + fl];
            a.x += v0.x; a.y += v0.y; a.z += v0.z; a.w += v0.w;
        }
        #pragma unroll
        for (int off = 8; off < 64; off <<= 1) {
            a.x += __shfl_xor(a.x, off);
            a.y += __shfl_xor(a.y, off);
            a.z += __shfl_xor(a.z, off);
            a.w += __shfl_xor(a.w, off);
        }
        if (lane < 8) {
            float inv = (dg > 0) ? 1.0f / (float)dg : 0.0f;
            float4 r; r.x = a.x * inv; r.y = a.y * inv; r.z = a.z * inv; r.w = a.w * inv;
            ((float4*)nbr_mean)[(size_t)n * 8 + fl] = r;
        }
    }
}

// ---- 6. fused node kernel: weights in registers, readlane broadcast
__global__ __launch_bounds__(256, 2) void node_kernel(
    const float* __restrict__ u, const float* __restrict__ intensity,
    const float* __restrict__ nbr_mean,
    const float* __restrict__ Wf, const float* __restrict__ bf,
    const float* __restrict__ Wg, const float* __restrict__ bg,
    const float* __restrict__ Wz, const float* __restrict__ bz,
    const float* __restrict__ WA, const float* __restrict__ bA,
    float* __restrict__ out, int N) {
    __shared__ float sWf[64 * 65];
    __shared__ float sWg[64 * 65];
    __shared__ float sW3[64 * 65];
    int tid = threadIdx.x;
    for (int idx = tid; idx < 4096; idx += 256) {
        int i = idx >> 6, k = idx & 63;
        sWf[i * 65 + k] = Wf[idx];
        sWg[i * 65 + k] = Wg[idx];
        sW3[i * 65 + k] = (i < 32) ? Wz[i * 64 + k] : WA[(i - 32) * 64 + k];
    }
    __syncthreads();

    int lane = tid & 63;
    int wave = tid >> 6;

    float wf[64], wg[64], w3[64];
    #pragma unroll
    for (int k = 0; k < 64; ++k) {
        wf[k] = sWf[lane * 65 + k];
        wg[k] = sWg[lane * 65 + k];
        w3[k] = sW3[lane * 65 + k];
    }
    float fb = bf[lane];
    float gb = bg[lane];
    float zb = (lane < 32) ? bz[lane] : bA[lane - 32];

    int gwave = blockIdx.x * 4 + wave;
    int wstride = gridDim.x * 4;
    for (int n = gwave; n < N; n += wstride) {
        float uval = u[(size_t)n * 64 + lane];
        float xval = (lane < 32) ? intensity[(size_t)n * 32 + lane]
                                 : nbr_mean[(size_t)n * 32 + (lane - 32)];
        float fA = fb, gA = gb, zA = zb;
        #pragma unroll
        for (int k = 0; k < 64; ++k) {
            float uk = bcastf(uval, k);
            float xk = bcastf(xval, k);
            float in3 = (lane < 32) ? uk : xk;
            fA = fmaf(wf[k], uk, fA);
            gA = fmaf(wg[k], uk, gA);
            zA = fmaf(w3[k], in3, zA);
        }
        float Fu = softplus_f(fA);
        float Gu = softplus_f(gA);
        float zv = (lane < 32) ? tanhf(zA) : fmaxf(zA, 0.0f);
        float du = -Fu * uval + Gu * zv;

        float a = (lane < 32) ? du * uval : 0.0f;
        float b = (lane < 32) ? uval * uval : 0.0f;
        #pragma unroll
        for (int off = 32; off; off >>= 1) {
            a += __shfl_xor(a, off);
            b += __shfl_xor(b, off);
        }
        out[(size_t)n * 64 + lane] = (lane < 32) ? (du - (a / b) * uval) : du;
    }
}

extern "C" void kernel_launch(void* const* d_in, const int* in_sizes, int n_in,
                              void* d_out, int out_size, void* d_ws, size_t ws_size,
                              hipStream_t stream) {
    const float* u         = (const float*)d_in[0];
    const float* intensity = (const float*)d_in[1];
    const int*   esrc      = (const int*)d_in[2];
    const int*   edst      = (const int*)d_in[3];
    const float* Wf        = (const float*)d_in[4];
    const float* bf        = (const float*)d_in[5];
    const float* Wg        = (const float*)d_in[6];
    const float* bg        = (const float*)d_in[7];
    const float* Wz        = (const float*)d_in[8];
    const float* bz        = (const float*)d_in[9];
    const float* WA        = (const float*)d_in[10];
    const float* bA        = (const float*)d_in[11];

    int N = in_sizes[0] / 64;
    int E = in_sizes[2];
    int B = (N + RNODES - 1) / RNODES;          // 782
    int M = B * NBLK;                            // 125120
    int nb = (M + 1023) / 1024;                  // 123 (<=128)

    int* cnt       = (int*)d_ws;                 // M
    int* offs      = cnt + M;                    // M
    int* bsum      = offs + M;                   // 128
    int* binned    = bsum + 128;                 // E
    int* nodestart = binned + E;                 // N
    int* degarr    = nodestart + N;              // N
    float* nbr_mean = (float*)(degarr + N);      // N*32

    bin_count<<<NBLK, 1024, 0, stream>>>(edst, cnt, E, B);
    scan_reduce<<<nb, 1024, 0, stream>>>(cnt, bsum, M);
    scan_top<<<1, 128, 0, stream>>>(bsum, nb);
    scan_final<<<nb, 1024, 0, stream>>>(cnt, bsum, offs, M);
    bin_scatter<<<NBLK, 1024, 0, stream>>>(esrc, edst, offs, binned, E, B);
    node_sort<<<B, 256, 0, stream>>>(binned, offs, nodestart, degarr, E, N, B);
    gather_kernel<<<2048, 256, 0, stream>>>(intensity, binned, nodestart, degarr,
                                            nbr_mean, N);
    node_kernel<<<1024, 256, 0, stream>>>(u, intensity, nbr_mean, Wf, bf, Wg, bg,
                                          Wz, bz, WA, bA, (float*)d_out, N);
}

// Round 6
// 198.772 us; speedup vs baseline: 4.4635x; 1.3729x over previous
//
#include <hip/hip_runtime.h>

// N=100000 nodes, D=64, P=Q=32, E=3200000 edges.
// Pipeline: bucket partition (radix by dst>>7) -> in-place node sort ->
// per-node CSR gather (writes nbr_mean as bf16) -> MFMA node kernel
// (bf16 16x16x32, 16 nodes/wave, 192 stacked output features).

#define RLOG 7
#define RNODES 128
#define NBLK 160
#define CAP 6144

typedef __attribute__((ext_vector_type(8))) short short8;
typedef __attribute__((ext_vector_type(4))) float f32x4;

__device__ __forceinline__ float softplus_f(float x) {
    return fmaxf(x, 0.0f) + log1pf(expf(-fabsf(x)));
}

__device__ __forceinline__ unsigned short f2bf(float x) {
    union { float f; unsigned u; } v; v.f = x;
    unsigned r = v.u + 0x7FFF + ((v.u >> 16) & 1);  // RNE
    return (unsigned short)(r >> 16);
}

// ---- 1. per-block bucket histogram: cnt[b*NBLK + blk]
__global__ __launch_bounds__(1024) void bin_count(const int* __restrict__ edst,
                                                  int* __restrict__ cnt,
                                                  int E, int B) {
    __shared__ int lcnt[1024];
    int tid = threadIdx.x, blk = blockIdx.x;
    for (int b = tid; b < B; b += 1024) lcnt[b] = 0;
    __syncthreads();
    int chunk = (E + NBLK - 1) / NBLK;
    int start = blk * chunk;
    int end = min(E, start + chunk);
    for (int i = start + tid; i < end; i += 1024)
        atomicAdd(&lcnt[edst[i] >> RLOG], 1);
    __syncthreads();
    for (int b = tid; b < B; b += 1024) cnt[b * NBLK + blk] = lcnt[b];
}

// ---- 2a. per-block partial sums
__global__ __launch_bounds__(1024) void scan_reduce(const int* __restrict__ cnt,
                                                    int* __restrict__ bsum, int M) {
    int idx = blockIdx.x * 1024 + threadIdx.x;
    int v = (idx < M) ? cnt[idx] : 0;
    #pragma unroll
    for (int off = 32; off; off >>= 1) v += __shfl_xor(v, off);
    __shared__ int wtot[16];
    int lane = threadIdx.x & 63, wave = threadIdx.x >> 6;
    if (lane == 0) wtot[wave] = v;
    __syncthreads();
    if (threadIdx.x == 0) {
        int s = 0;
        #pragma unroll
        for (int i = 0; i < 16; ++i) s += wtot[i];
        bsum[blockIdx.x] = s;
    }
}

// ---- 2b. exclusive scan of block sums (nb <= 128)
__global__ void scan_top(int* __restrict__ bsum, int nb) {
    int t = threadIdx.x;
    int v = (t < nb) ? bsum[t] : 0;
    int lane = t & 63, wave = t >> 6;
    int incl = v;
    #pragma unroll
    for (int off = 1; off < 64; off <<= 1) {
        int w = __shfl_up(incl, off);
        if (lane >= off) incl += w;
    }
    __shared__ int wt[2];
    if (lane == 63) wt[wave] = incl;
    __syncthreads();
    int excl = incl - v + ((wave == 1) ? wt[0] : 0);
    if (t < nb) bsum[t] = excl;
}

// ---- 2c. final exclusive scan -> offs
__global__ __launch_bounds__(1024) void scan_final(const int* __restrict__ cnt,
                                                   const int* __restrict__ bsum,
                                                   int* __restrict__ offs, int M) {
    int t = threadIdx.x;
    int idx = blockIdx.x * 1024 + t;
    int lane = t & 63, wave = t >> 6;
    int v = (idx < M) ? cnt[idx] : 0;
    int incl = v;
    #pragma unroll
    for (int off = 1; off < 64; off <<= 1) {
        int w = __shfl_up(incl, off);
        if (lane >= off) incl += w;
    }
    __shared__ int wtot[16];
    if (lane == 63) wtot[wave] = incl;
    __syncthreads();
    int woff = 0;
    for (int i = 0; i < wave; ++i) woff += wtot[i];
    if (idx < M) offs[idx] = bsum[blockIdx.x] + woff + incl - v;
}

// ---- 3. scatter packed entries using LDS cursors
__global__ __launch_bounds__(1024) void bin_scatter(const int* __restrict__ esrc,
                                                    const int* __restrict__ edst,
                                                    const int* __restrict__ offs,
                                                    int* __restrict__ binned,
                                                    int E, int B) {
    __shared__ int lcur[1024];
    int tid = threadIdx.x, blk = blockIdx.x;
    for (int b = tid; b < B; b += 1024) lcur[b] = offs[b * NBLK + blk];
    __syncthreads();
    int chunk = (E + NBLK - 1) / NBLK;
    int start = blk * chunk;
    int end = min(E, start + chunk);
    for (int i = start + tid; i < end; i += 1024) {
        int d = edst[i];
        int s = esrc[i];
        int b = d >> RLOG;
        int pos = atomicAdd(&lcur[b], 1);
        binned[pos] = ((d & (RNODES - 1)) << 17) | s;
    }
}

// ---- 4. in-place node sort within each bucket
__global__ __launch_bounds__(256) void node_sort(int* __restrict__ binned,
                                                 const int* __restrict__ offs,
                                                 int* __restrict__ nodestart,
                                                 int* __restrict__ degarr,
                                                 int E, int N, int B) {
    __shared__ int sl[CAP];
    __shared__ int c128[RNODES];
    __shared__ int pos[RNODES];
    int tid = threadIdx.x;
    int b = blockIdx.x;
    int start = offs[b * NBLK];
    int end = (b + 1 < B) ? offs[(b + 1) * NBLK] : E;
    int m = min(end - start, CAP);

    for (int i = tid; i < m; i += 256) sl[i] = binned[start + i];
    if (tid < RNODES) c128[tid] = 0;
    __syncthreads();
    for (int i = tid; i < m; i += 256) atomicAdd(&c128[sl[i] >> 17], 1);
    __syncthreads();

    int x = 0, incl = 0;
    if (tid < RNODES) { x = c128[tid]; incl = x; }
    #pragma unroll
    for (int off = 1; off < RNODES; off <<= 1) {
        int y = 0;
        if (tid < RNODES && tid >= off) y = c128[tid - off];
        __syncthreads();
        if (tid < RNODES) { incl += y; c128[tid] = incl; }
        __syncthreads();
    }
    if (tid < RNODES) {
        int excl = incl - x;
        pos[tid] = excl;
        int node = b * RNODES + tid;
        if (node < N) {
            nodestart[node] = start + excl;
            degarr[node] = x;
        }
    }
    __syncthreads();
    for (int i = tid; i < m; i += 256) {
        int e = sl[i];
        int p = atomicAdd(&pos[e >> 17], 1);
        binned[start + p] = e & 131071;
    }
}

// ---- 5. gather: one wave per node, writes nbr_mean as bf16 into xnbr
__global__ __launch_bounds__(256) void gather_kernel(
    const float* __restrict__ intensity, const int* __restrict__ binned,
    const int* __restrict__ nodestart, const int* __restrict__ degarr,
    unsigned short* __restrict__ xnbr, int N) {
    int lane = threadIdx.x & 63;
    int wave = threadIdx.x >> 6;
    int gid = lane >> 3;
    int fl = lane & 7;
    int gwave = blockIdx.x * 4 + wave;
    int wstride = gridDim.x * 4;
    for (int n = gwave; n < N; n += wstride) {
        int st = nodestart[n];
        int dg = degarr[n];
        float4 a = make_float4(0.f, 0.f, 0.f, 0.f);
        int j = gid;
        for (; j + 8 < dg; j += 16) {
            int s0 = binned[st + j];
            int s1 = binned[st + j + 8];
            float4 v0 = ((const float4*)intensity)[(size_t)s0 * 8 + fl];
            float4 v1 = ((const float4*)intensity)[(size_t)s1 * 8 + fl];
            a.x += v0.x + v1.x; a.y += v0.y + v1.y;
            a.z += v0.z + v1.z; a.w += v0.w + v1.w;
        }
        if (j < dg) {
            int s0 = binned[st + j];
            float4 v0 = ((const float4*)intensity)[(size_t)s0 * 8 + fl];
            a.x += v0.x; a.y += v0.y; a.z += v0.z; a.w += v0.w;
        }
        #pragma unroll
        for (int off = 8; off < 64; off <<= 1) {
            a.x += __shfl_xor(a.x, off);
            a.y += __shfl_xor(a.y, off);
            a.z += __shfl_xor(a.z, off);
            a.w += __shfl_xor(a.w, off);
        }
        if (lane < 8) {
            float inv = (dg > 0) ? 1.0f / (float)dg : 0.0f;
            ushort4 r;
            r.x = f2bf(a.x * inv); r.y = f2bf(a.y * inv);
            r.z = f2bf(a.z * inv); r.w = f2bf(a.w * inv);
            *(ushort4*)(xnbr + (size_t)n * 32 + fl * 4) = r;
        }
    }
}

// ---- 6. build stacked bf16 weight matrix Wbig[192][64]
// rows 0-63: Wf, 64-127: Wg, 128-159: Wz, 160-191: WA
__global__ __launch_bounds__(256) void prep_w(const float* __restrict__ Wf,
                                              const float* __restrict__ Wg,
                                              const float* __restrict__ Wz,
                                              const float* __restrict__ WA,
                                              unsigned short* __restrict__ wbig) {
    int idx = blockIdx.x * 256 + threadIdx.x;
    if (idx >= 192 * 64) return;
    int r = idx >> 6, k = idx & 63;
    float v = (r < 64)  ? Wf[r * 64 + k]
            : (r < 128) ? Wg[(r - 64) * 64 + k]
            : (r < 160) ? Wz[(r - 128) * 64 + k]
                        : WA[(r - 160) * 64 + k];
    wbig[idx] = f2bf(v);
}

// ---- 7. MFMA node kernel: one wave = 16 nodes, 12 feature-tiles x K=64
#define HPAD 194
__global__ __launch_bounds__(256, 3) void node_mfma(
    const float* __restrict__ u, const float* __restrict__ intensity,
    const unsigned short* __restrict__ xnbr,
    const unsigned short* __restrict__ wbig,
    const float* __restrict__ bfp, const float* __restrict__ bgp,
    const float* __restrict__ bzp, const float* __restrict__ bAp,
    float* __restrict__ out, int N) {
    __shared__ float Hlds[4][16 * HPAD];
    int tid = threadIdx.x;
    int lane = tid & 63;
    int wave = tid >> 6;
    int tile = blockIdx.x * 4 + wave;
    int ntiles = N >> 4;                 // N divisible by 16
    if (tile >= ntiles) return;

    int col = lane & 15;                 // node-in-tile (A row / D col-group)
    int kg = lane >> 4;                  // k-group / D row-group
    int n0 = tile * 16;
    int node = n0 + col;

    // A-fragments: u (k 0..63) and x = [intensity | nbr] (k 0..63)
    const float* ub = u + (size_t)node * 64 + kg * 8;
    float4 u0 = *(const float4*)(ub);
    float4 u1 = *(const float4*)(ub + 4);
    float4 u2 = *(const float4*)(ub + 32);
    float4 u3 = *(const float4*)(ub + 36);
    const float* ib = intensity + (size_t)node * 32 + kg * 8;
    float4 i0 = *(const float4*)(ib);
    float4 i1 = *(const float4*)(ib + 4);
    short8 au0, au1, ax0;
    au0[0]=(short)f2bf(u0.x); au0[1]=(short)f2bf(u0.y); au0[2]=(short)f2bf(u0.z); au0[3]=(short)f2bf(u0.w);
    au0[4]=(short)f2bf(u1.x); au0[5]=(short)f2bf(u1.y); au0[6]=(short)f2bf(u1.z); au0[7]=(short)f2bf(u1.w);
    au1[0]=(short)f2bf(u2.x); au1[1]=(short)f2bf(u2.y); au1[2]=(short)f2bf(u2.z); au1[3]=(short)f2bf(u2.w);
    au1[4]=(short)f2bf(u3.x); au1[5]=(short)f2bf(u3.y); au1[6]=(short)f2bf(u3.z); au1[7]=(short)f2bf(u3.w);
    ax0[0]=(short)f2bf(i0.x); ax0[1]=(short)f2bf(i0.y); ax0[2]=(short)f2bf(i0.z); ax0[3]=(short)f2bf(i0.w);
    ax0[4]=(short)f2bf(i1.x); ax0[5]=(short)f2bf(i1.y); ax0[6]=(short)f2bf(i1.z); ax0[7]=(short)f2bf(i1.w);
    short8 ax1 = *(const short8*)(xnbr + (size_t)node * 32 + kg * 8);

    const short8* wb = (const short8*)wbig;  // frag idx = (feat)*8 + s*4 + kg
    f32x4 acc[12];
    #pragma unroll
    for (int t = 0; t < 12; ++t) acc[t] = (f32x4){0.f, 0.f, 0.f, 0.f};
    #pragma unroll
    for (int t = 0; t < 12; ++t) {
        short8 a0 = (t < 10) ? au0 : ax0;
        short8 a1 = (t < 10) ? au1 : ax1;
        short8 b0 = wb[(t * 16 + col) * 8 + kg];
        short8 b1 = wb[(t * 16 + col) * 8 + 4 + kg];
        acc[t] = __builtin_amdgcn_mfma_f32_16x16x32_bf16(a0, b0, acc[t], 0, 0, 0);
        acc[t] = __builtin_amdgcn_mfma_f32_16x16x32_bf16(a1, b1, acc[t], 0, 0, 0);
    }

    // D -> LDS: lane (col,kg) reg r holds D[row=kg*4+r][feat=t*16+col]
    float* H = Hlds[wave];
    #pragma unroll
    for (int t = 0; t < 12; ++t) {
        #pragma unroll
        for (int r = 0; r < 4; ++r)
            H[(kg * 4 + r) * HPAD + t * 16 + col] = acc[t][r];
    }

    // epilogue: feature-per-lane over the wave's 16 nodes
    float bfv = bfp[lane];
    float bgv = bgp[lane];
    float bzv = (lane < 32) ? bzp[lane] : bAp[lane - 32];
    for (int nl = 0; nl < 16; ++nl) {
        int nd = n0 + nl;
        float fpre = H[nl * HPAD + lane] + bfv;
        float gpre = H[nl * HPAD + 64 + lane] + bgv;
        float zpre = H[nl * HPAD + 128 + lane] + bzv;
        float uval = u[(size_t)nd * 64 + lane];
        float Fu = softplus_f(fpre);
        float Gu = softplus_f(gpre);
        float zv = (lane < 32) ? tanhf(zpre) : fmaxf(zpre, 0.0f);
        float du = -Fu * uval + Gu * zv;
        float a = (lane < 32) ? du * uval : 0.0f;
        float b = (lane < 32) ? uval * uval : 0.0f;
        #pragma unroll
        for (int off = 32; off; off >>= 1) {
            a += __shfl_xor(a, off);
            b += __shfl_xor(b, off);
        }
        out[(size_t)nd * 64 + lane] = (lane < 32) ? (du - (a / b) * uval) : du;
    }
}

extern "C" void kernel_launch(void* const* d_in, const int* in_sizes, int n_in,
                              void* d_out, int out_size, void* d_ws, size_t ws_size,
                              hipStream_t stream) {
    const float* u         = (const float*)d_in[0];
    const float* intensity = (const float*)d_in[1];
    const int*   esrc      = (const int*)d_in[2];
    const int*   edst      = (const int*)d_in[3];
    const float* Wf        = (const float*)d_in[4];
    const float* bf        = (const float*)d_in[5];
    const float* Wg        = (const float*)d_in[6];
    const float* bg        = (const float*)d_in[7];
    const float* Wz        = (const float*)d_in[8];
    const float* bz        = (const float*)d_in[9];
    const float* WA        = (const float*)d_in[10];
    const float* bA        = (const float*)d_in[11];

    int N = in_sizes[0] / 64;
    int E = in_sizes[2];
    int B = (N + RNODES - 1) / RNODES;          // 782
    int M = B * NBLK;                            // 125120
    int nb = (M + 1023) / 1024;                  // 123

    int* cnt       = (int*)d_ws;                 // M
    int* offs      = cnt + M;                    // M
    int* bsum      = offs + M;                   // 128
    int* binned    = bsum + 128;                 // E
    int* nodestart = binned + E;                 // N
    int* degarr    = nodestart + N;              // N
    unsigned short* xnbr = (unsigned short*)(degarr + N);   // N*32
    unsigned short* wbig = xnbr + (size_t)N * 32;           // 192*64

    prep_w<<<48, 256, 0, stream>>>(Wf, Wg, Wz, WA, wbig);
    bin_count<<<NBLK, 1024, 0, stream>>>(edst, cnt, E, B);
    scan_reduce<<<nb, 1024, 0, stream>>>(cnt, bsum, M);
    scan_top<<<1, 128, 0, stream>>>(bsum, nb);
    scan_final<<<nb, 1024, 0, stream>>>(cnt, bsum, offs, M);
    bin_scatter<<<NBLK, 1024, 0, stream>>>(esrc, edst, offs, binned, E, B);
    node_sort<<<B, 256, 0, stream>>>(binned, offs, nodestart, degarr, E, N, B);
    gather_kernel<<<2048, 256, 0, stream>>>(intensity, binned, nodestart, degarr,
                                            xnbr, N);
    int ntiles = N / 16;                         // 6250
    int nblocks = (ntiles + 3) / 4;              // 1563
    node_mfma<<<nblocks, 256, 0, stream>>>(u, intensity, xnbr, wbig,
                                           bf, bg, bz, bA, (float*)d_out, N);
}

// Round 7
// 164.961 us; speedup vs baseline: 5.3784x; 1.2050x over previous
//
#include <hip/hip_runtime.h>

// N=100000 nodes, D=64, P=Q=32, E=3200000 edges.
// Pipeline: bucket partition (radix by dst>>7) -> in-place node sort ->
// per-node CSR gather (writes nbr_mean as bf16) -> MFMA node kernel
// (bf16 16x16x32, 16 nodes/wave, 192 stacked output features) with
// fast-transcendental epilogue.

#define RLOG 7
#define RNODES 128
#define NBLK 160
#define CAP 6144

typedef __attribute__((ext_vector_type(8))) short short8;
typedef __attribute__((ext_vector_type(4))) float f32x4;

__device__ __forceinline__ unsigned short f2bf(float x) {
    union { float f; unsigned u; } v; v.f = x;
    unsigned r = v.u + 0x7FFF + ((v.u >> 16) & 1);  // RNE
    return (unsigned short)(r >> 16);
}

// fast softplus: max(x,0) + log(1+exp(-|x|)) via v_exp_f32/v_log_f32
__device__ __forceinline__ float softplus_fast(float x) {
    float t = __expf(-fabsf(x));
    return fmaxf(x, 0.0f) + __logf(1.0f + t);
}

// fast tanh: sign(x) * (1-t)/(1+t), t = exp(-2|x|)
__device__ __forceinline__ float tanh_fast(float x) {
    float t = __expf(-2.0f * fabsf(x));
    float m = (1.0f - t) * __builtin_amdgcn_rcpf(1.0f + t);
    return __builtin_copysignf(m, x);
}

// ---- 1. per-block bucket histogram: cnt[b*NBLK + blk]
__global__ __launch_bounds__(1024) void bin_count(const int* __restrict__ edst,
                                                  int* __restrict__ cnt,
                                                  int E, int B) {
    __shared__ int lcnt[1024];
    int tid = threadIdx.x, blk = blockIdx.x;
    for (int b = tid; b < B; b += 1024) lcnt[b] = 0;
    __syncthreads();
    int chunk = (E + NBLK - 1) / NBLK;
    int start = blk * chunk;
    int end = min(E, start + chunk);
    for (int i = start + tid; i < end; i += 1024)
        atomicAdd(&lcnt[edst[i] >> RLOG], 1);
    __syncthreads();
    for (int b = tid; b < B; b += 1024) cnt[b * NBLK + blk] = lcnt[b];
}

// ---- 2a. per-block partial sums
__global__ __launch_bounds__(1024) void scan_reduce(const int* __restrict__ cnt,
                                                    int* __restrict__ bsum, int M) {
    int idx = blockIdx.x * 1024 + threadIdx.x;
    int v = (idx < M) ? cnt[idx] : 0;
    #pragma unroll
    for (int off = 32; off; off >>= 1) v += __shfl_xor(v, off);
    __shared__ int wtot[16];
    int lane = threadIdx.x & 63, wave = threadIdx.x >> 6;
    if (lane == 0) wtot[wave] = v;
    __syncthreads();
    if (threadIdx.x == 0) {
        int s = 0;
        #pragma unroll
        for (int i = 0; i < 16; ++i) s += wtot[i];
        bsum[blockIdx.x] = s;
    }
}

// ---- 2b. exclusive scan of block sums (nb <= 128)
__global__ void scan_top(int* __restrict__ bsum, int nb) {
    int t = threadIdx.x;
    int v = (t < nb) ? bsum[t] : 0;
    int lane = t & 63, wave = t >> 6;
    int incl = v;
    #pragma unroll
    for (int off = 1; off < 64; off <<= 1) {
        int w = __shfl_up(incl, off);
        if (lane >= off) incl += w;
    }
    __shared__ int wt[2];
    if (lane == 63) wt[wave] = incl;
    __syncthreads();
    int excl = incl - v + ((wave == 1) ? wt[0] : 0);
    if (t < nb) bsum[t] = excl;
}

// ---- 2c. final exclusive scan -> offs
__global__ __launch_bounds__(1024) void scan_final(const int* __restrict__ cnt,
                                                   const int* __restrict__ bsum,
                                                   int* __restrict__ offs, int M) {
    int t = threadIdx.x;
    int idx = blockIdx.x * 1024 + t;
    int lane = t & 63, wave = t >> 6;
    int v = (idx < M) ? cnt[idx] : 0;
    int incl = v;
    #pragma unroll
    for (int off = 1; off < 64; off <<= 1) {
        int w = __shfl_up(incl, off);
        if (lane >= off) incl += w;
    }
    __shared__ int wtot[16];
    if (lane == 63) wtot[wave] = incl;
    __syncthreads();
    int woff = 0;
    for (int i = 0; i < wave; ++i) woff += wtot[i];
    if (idx < M) offs[idx] = bsum[blockIdx.x] + woff + incl - v;
}

// ---- 3. scatter packed entries using LDS cursors
__global__ __launch_bounds__(1024) void bin_scatter(const int* __restrict__ esrc,
                                                    const int* __restrict__ edst,
                                                    const int* __restrict__ offs,
                                                    int* __restrict__ binned,
                                                    int E, int B) {
    __shared__ int lcur[1024];
    int tid = threadIdx.x, blk = blockIdx.x;
    for (int b = tid; b < B; b += 1024) lcur[b] = offs[b * NBLK + blk];
    __syncthreads();
    int chunk = (E + NBLK - 1) / NBLK;
    int start = blk * chunk;
    int end = min(E, start + chunk);
    for (int i = start + tid; i < end; i += 1024) {
        int d = edst[i];
        int s = esrc[i];
        int b = d >> RLOG;
        int pos = atomicAdd(&lcur[b], 1);
        binned[pos] = ((d & (RNODES - 1)) << 17) | s;
    }
}

// ---- 4. in-place node sort within each bucket
__global__ __launch_bounds__(256) void node_sort(int* __restrict__ binned,
                                                 const int* __restrict__ offs,
                                                 int* __restrict__ nodestart,
                                                 int* __restrict__ degarr,
                                                 int E, int N, int B) {
    __shared__ int sl[CAP];
    __shared__ int c128[RNODES];
    __shared__ int pos[RNODES];
    int tid = threadIdx.x;
    int b = blockIdx.x;
    int start = offs[b * NBLK];
    int end = (b + 1 < B) ? offs[(b + 1) * NBLK] : E;
    int m = min(end - start, CAP);

    for (int i = tid; i < m; i += 256) sl[i] = binned[start + i];
    if (tid < RNODES) c128[tid] = 0;
    __syncthreads();
    for (int i = tid; i < m; i += 256) atomicAdd(&c128[sl[i] >> 17], 1);
    __syncthreads();

    int x = 0, incl = 0;
    if (tid < RNODES) { x = c128[tid]; incl = x; }
    #pragma unroll
    for (int off = 1; off < RNODES; off <<= 1) {
        int y = 0;
        if (tid < RNODES && tid >= off) y = c128[tid - off];
        __syncthreads();
        if (tid < RNODES) { incl += y; c128[tid] = incl; }
        __syncthreads();
    }
    if (tid < RNODES) {
        int excl = incl - x;
        pos[tid] = excl;
        int node = b * RNODES + tid;
        if (node < N) {
            nodestart[node] = start + excl;
            degarr[node] = x;
        }
    }
    __syncthreads();
    for (int i = tid; i < m; i += 256) {
        int e = sl[i];
        int p = atomicAdd(&pos[e >> 17], 1);
        binned[start + p] = e & 131071;
    }
}

// ---- 5. gather: one wave per node, writes nbr_mean as bf16 into xnbr
__global__ __launch_bounds__(256) void gather_kernel(
    const float* __restrict__ intensity, const int* __restrict__ binned,
    const int* __restrict__ nodestart, const int* __restrict__ degarr,
    unsigned short* __restrict__ xnbr, int N) {
    int lane = threadIdx.x & 63;
    int wave = threadIdx.x >> 6;
    int gid = lane >> 3;
    int fl = lane & 7;
    int gwave = blockIdx.x * 4 + wave;
    int wstride = gridDim.x * 4;
    for (int n = gwave; n < N; n += wstride) {
        int st = nodestart[n];
        int dg = degarr[n];
        float4 a = make_float4(0.f, 0.f, 0.f, 0.f);
        int j = gid;
        for (; j + 8 < dg; j += 16) {
            int s0 = binned[st + j];
            int s1 = binned[st + j + 8];
            float4 v0 = ((const float4*)intensity)[(size_t)s0 * 8 + fl];
            float4 v1 = ((const float4*)intensity)[(size_t)s1 * 8 + fl];
            a.x += v0.x + v1.x; a.y += v0.y + v1.y;
            a.z += v0.z + v1.z; a.w += v0.w + v1.w;
        }
        if (j < dg) {
            int s0 = binned[st + j];
            float4 v0 = ((const float4*)intensity)[(size_t)s0 * 8 + fl];
            a.x += v0.x; a.y += v0.y; a.z += v0.z; a.w += v0.w;
        }
        #pragma unroll
        for (int off = 8; off < 64; off <<= 1) {
            a.x += __shfl_xor(a.x, off);
            a.y += __shfl_xor(a.y, off);
            a.z += __shfl_xor(a.z, off);
            a.w += __shfl_xor(a.w, off);
        }
        if (lane < 8) {
            float inv = (dg > 0) ? 1.0f / (float)dg : 0.0f;
            ushort4 r;
            r.x = f2bf(a.x * inv); r.y = f2bf(a.y * inv);
            r.z = f2bf(a.z * inv); r.w = f2bf(a.w * inv);
            *(ushort4*)(xnbr + (size_t)n * 32 + fl * 4) = r;
        }
    }
}

// ---- 6. build stacked bf16 weight matrix Wbig[192][64]
__global__ __launch_bounds__(256) void prep_w(const float* __restrict__ Wf,
                                              const float* __restrict__ Wg,
                                              const float* __restrict__ Wz,
                                              const float* __restrict__ WA,
                                              unsigned short* __restrict__ wbig) {
    int idx = blockIdx.x * 256 + threadIdx.x;
    if (idx >= 192 * 64) return;
    int r = idx >> 6, k = idx & 63;
    float v = (r < 64)  ? Wf[r * 64 + k]
            : (r < 128) ? Wg[(r - 64) * 64 + k]
            : (r < 160) ? Wz[(r - 128) * 64 + k]
                        : WA[(r - 160) * 64 + k];
    wbig[idx] = f2bf(v);
}

// ---- 7. MFMA node kernel: one wave = 16 nodes, 12 feature-tiles x K=64
#define HPAD 194
__global__ __launch_bounds__(256, 3) void node_mfma(
    const float* __restrict__ u, const float* __restrict__ intensity,
    const unsigned short* __restrict__ xnbr,
    const unsigned short* __restrict__ wbig,
    const float* __restrict__ bfp, const float* __restrict__ bgp,
    const float* __restrict__ bzp, const float* __restrict__ bAp,
    float* __restrict__ out, int N) {
    __shared__ float Hlds[4][16 * HPAD];
    int tid = threadIdx.x;
    int lane = tid & 63;
    int wave = tid >> 6;
    int tile = blockIdx.x * 4 + wave;
    int ntiles = N >> 4;
    if (tile >= ntiles) return;

    int col = lane & 15;
    int kg = lane >> 4;
    int n0 = tile * 16;
    int node = n0 + col;

    const float* ub = u + (size_t)node * 64 + kg * 8;
    float4 u0 = *(const float4*)(ub);
    float4 u1 = *(const float4*)(ub + 4);
    float4 u2 = *(const float4*)(ub + 32);
    float4 u3 = *(const float4*)(ub + 36);
    const float* ib = intensity + (size_t)node * 32 + kg * 8;
    float4 i0 = *(const float4*)(ib);
    float4 i1 = *(const float4*)(ib + 4);
    short8 au0, au1, ax0;
    au0[0]=(short)f2bf(u0.x); au0[1]=(short)f2bf(u0.y); au0[2]=(short)f2bf(u0.z); au0[3]=(short)f2bf(u0.w);
    au0[4]=(short)f2bf(u1.x); au0[5]=(short)f2bf(u1.y); au0[6]=(short)f2bf(u1.z); au0[7]=(short)f2bf(u1.w);
    au1[0]=(short)f2bf(u2.x); au1[1]=(short)f2bf(u2.y); au1[2]=(short)f2bf(u2.z); au1[3]=(short)f2bf(u2.w);
    au1[4]=(short)f2bf(u3.x); au1[5]=(short)f2bf(u3.y); au1[6]=(short)f2bf(u3.z); au1[7]=(short)f2bf(u3.w);
    ax0[0]=(short)f2bf(i0.x); ax0[1]=(short)f2bf(i0.y); ax0[2]=(short)f2bf(i0.z); ax0[3]=(short)f2bf(i0.w);
    ax0[4]=(short)f2bf(i1.x); ax0[5]=(short)f2bf(i1.y); ax0[6]=(short)f2bf(i1.z); ax0[7]=(short)f2bf(i1.w);
    short8 ax1 = *(const short8*)(xnbr + (size_t)node * 32 + kg * 8);

    const short8* wb = (const short8*)wbig;
    f32x4 acc[12];
    #pragma unroll
    for (int t = 0; t < 12; ++t) acc[t] = (f32x4){0.f, 0.f, 0.f, 0.f};
    #pragma unroll
    for (int t = 0; t < 12; ++t) {
        short8 a0 = (t < 10) ? au0 : ax0;
        short8 a1 = (t < 10) ? au1 : ax1;
        short8 b0 = wb[(t * 16 + col) * 8 + kg];
        short8 b1 = wb[(t * 16 + col) * 8 + 4 + kg];
        acc[t] = __builtin_amdgcn_mfma_f32_16x16x32_bf16(a0, b0, acc[t], 0, 0, 0);
        acc[t] = __builtin_amdgcn_mfma_f32_16x16x32_bf16(a1, b1, acc[t], 0, 0, 0);
    }

    float* H = Hlds[wave];
    #pragma unroll
    for (int t = 0; t < 12; ++t) {
        #pragma unroll
        for (int r = 0; r < 4; ++r)
            H[(kg * 4 + r) * HPAD + t * 16 + col] = acc[t][r];
    }

    float bfv = bfp[lane];
    float bgv = bgp[lane];
    float bzv = (lane < 32) ? bzp[lane] : bAp[lane - 32];
    #pragma unroll 4
    for (int nl = 0; nl < 16; ++nl) {
        int nd = n0 + nl;
        float fpre = H[nl * HPAD + lane] + bfv;
        float gpre = H[nl * HPAD + 64 + lane] + bgv;
        float zpre = H[nl * HPAD + 128 + lane] + bzv;
        float uval = u[(size_t)nd * 64 + lane];
        float Fu = softplus_fast(fpre);
        float Gu = softplus_fast(gpre);
        float zv = (lane < 32) ? tanh_fast(zpre) : fmaxf(zpre, 0.0f);
        float du = -Fu * uval + Gu * zv;
        // projection: values live in lanes<32; xor-offsets <=16 stay in-half
        float a = du * uval;
        float b = uval * uval;
        #pragma unroll
        for (int off = 16; off; off >>= 1) {
            a += __shfl_xor(a, off);
            b += __shfl_xor(b, off);
        }
        float res = (lane < 32) ? (du - a * __builtin_amdgcn_rcpf(b) * uval) : du;
        out[(size_t)nd * 64 + lane] = res;
    }
}

extern "C" void kernel_launch(void* const* d_in, const int* in_sizes, int n_in,
                              void* d_out, int out_size, void* d_ws, size_t ws_size,
                              hipStream_t stream) {
    const float* u         = (const float*)d_in[0];
    const float* intensity = (const float*)d_in[1];
    const int*   esrc      = (const int*)d_in[2];
    const int*   edst      = (const int*)d_in[3];
    const float* Wf        = (const float*)d_in[4];
    const float* bf        = (const float*)d_in[5];
    const float* Wg        = (const float*)d_in[6];
    const float* bg        = (const float*)d_in[7];
    const float* Wz        = (const float*)d_in[8];
    const float* bz        = (const float*)d_in[9];
    const float* WA        = (const float*)d_in[10];
    const float* bA        = (const float*)d_in[11];

    int N = in_sizes[0] / 64;
    int E = in_sizes[2];
    int B = (N + RNODES - 1) / RNODES;
    int M = B * NBLK;
    int nb = (M + 1023) / 1024;

    int* cnt       = (int*)d_ws;
    int* offs      = cnt + M;
    int* bsum      = offs + M;
    int* binned    = bsum + 128;
    int* nodestart = binned + E;
    int* degarr    = nodestart + N;
    unsigned short* xnbr = (unsigned short*)(degarr + N);
    unsigned short* wbig = xnbr + (size_t)N * 32;

    prep_w<<<48, 256, 0, stream>>>(Wf, Wg, Wz, WA, wbig);
    bin_count<<<NBLK, 1024, 0, stream>>>(edst, cnt, E, B);
    scan_reduce<<<nb, 1024, 0, stream>>>(cnt, bsum, M);
    scan_top<<<1, 128, 0, stream>>>(bsum, nb);
    scan_final<<<nb, 1024, 0, stream>>>(cnt, bsum, offs, M);
    bin_scatter<<<NBLK, 1024, 0, stream>>>(esrc, edst, offs, binned, E, B);
    node_sort<<<B, 256, 0, stream>>>(binned, offs, nodestart, degarr, E, N, B);
    gather_kernel<<<2048, 256, 0, stream>>>(intensity, binned, nodestart, degarr,
                                            xnbr, N);
    int ntiles = N / 16;
    int nblocks = (ntiles + 3) / 4;
    node_mfma<<<nblocks, 256, 0, stream>>>(u, intensity, xnbr, wbig,
                                           bf, bg, bz, bA, (float*)d_out, N);
}

// Round 8
// 160.088 us; speedup vs baseline: 5.5421x; 1.0304x over previous
//
#include <hip/hip_runtime.h>

// N=100000 nodes, D=64, P=Q=32, E=3200000 edges.
// Pipeline: bucket partition (radix by dst>>7, 256 partition blocks, int4
// edge loads) -> in-place node sort -> per-node CSR gather (bf16 out) ->
// MFMA node kernel (bf16 16x16x32, 16 nodes/wave) with fast transcendentals.

#define RLOG 7
#define RNODES 128
#define NBLK 256
#define CAP 6144

typedef __attribute__((ext_vector_type(8))) short short8;
typedef __attribute__((ext_vector_type(4))) float f32x4;

__device__ __forceinline__ unsigned short f2bf(float x) {
    union { float f; unsigned u; } v; v.f = x;
    unsigned r = v.u + 0x7FFF + ((v.u >> 16) & 1);  // RNE
    return (unsigned short)(r >> 16);
}

__device__ __forceinline__ float softplus_fast(float x) {
    float t = __expf(-fabsf(x));
    return fmaxf(x, 0.0f) + __logf(1.0f + t);
}

__device__ __forceinline__ float tanh_fast(float x) {
    float t = __expf(-2.0f * fabsf(x));
    float m = (1.0f - t) * __builtin_amdgcn_rcpf(1.0f + t);
    return __builtin_copysignf(m, x);
}

// chunk per partition block, multiple of 4
__device__ __forceinline__ int chunk_of(int E) {
    return (((E + NBLK - 1) / NBLK) + 3) & ~3;
}

// ---- 1. per-block bucket histogram: cnt[b*NBLK + blk]
__global__ __launch_bounds__(1024) void bin_count(const int* __restrict__ edst,
                                                  int* __restrict__ cnt,
                                                  int E, int B) {
    __shared__ int lcnt[1024];
    int tid = threadIdx.x, blk = blockIdx.x;
    for (int b = tid; b < B; b += 1024) lcnt[b] = 0;
    __syncthreads();
    int chunk = chunk_of(E);
    int start = blk * chunk;
    int end = min(E, start + chunk);
    int v4s = start >> 2, v4e = end >> 2;
    for (int i = v4s + tid; i < v4e; i += 1024) {
        int4 d = ((const int4*)edst)[i];
        atomicAdd(&lcnt[d.x >> RLOG], 1);
        atomicAdd(&lcnt[d.y >> RLOG], 1);
        atomicAdd(&lcnt[d.z >> RLOG], 1);
        atomicAdd(&lcnt[d.w >> RLOG], 1);
    }
    for (int i = (v4e << 2) + tid; i < end; i += 1024)
        atomicAdd(&lcnt[edst[i] >> RLOG], 1);
    __syncthreads();
    for (int b = tid; b < B; b += 1024) cnt[b * NBLK + blk] = lcnt[b];
}

// ---- 2a. per-block partial sums
__global__ __launch_bounds__(1024) void scan_reduce(const int* __restrict__ cnt,
                                                    int* __restrict__ bsum, int M) {
    int idx = blockIdx.x * 1024 + threadIdx.x;
    int v = (idx < M) ? cnt[idx] : 0;
    #pragma unroll
    for (int off = 32; off; off >>= 1) v += __shfl_xor(v, off);
    __shared__ int wtot[16];
    int lane = threadIdx.x & 63, wave = threadIdx.x >> 6;
    if (lane == 0) wtot[wave] = v;
    __syncthreads();
    if (threadIdx.x == 0) {
        int s = 0;
        #pragma unroll
        for (int i = 0; i < 16; ++i) s += wtot[i];
        bsum[blockIdx.x] = s;
    }
}

// ---- 2b. exclusive scan of block sums (single block, nb <= 1024)
__global__ __launch_bounds__(1024) void scan_top(int* __restrict__ bsum, int nb) {
    int t = threadIdx.x;
    int lane = t & 63, wave = t >> 6;
    int v = (t < nb) ? bsum[t] : 0;
    int incl = v;
    #pragma unroll
    for (int off = 1; off < 64; off <<= 1) {
        int w = __shfl_up(incl, off);
        if (lane >= off) incl += w;
    }
    __shared__ int wt[16];
    if (lane == 63) wt[wave] = incl;
    __syncthreads();
    int woff = 0;
    for (int i = 0; i < wave; ++i) woff += wt[i];
    if (t < nb) bsum[t] = woff + incl - v;
}

// ---- 2c. final exclusive scan -> offs
__global__ __launch_bounds__(1024) void scan_final(const int* __restrict__ cnt,
                                                   const int* __restrict__ bsum,
                                                   int* __restrict__ offs, int M) {
    int t = threadIdx.x;
    int idx = blockIdx.x * 1024 + t;
    int lane = t & 63, wave = t >> 6;
    int v = (idx < M) ? cnt[idx] : 0;
    int incl = v;
    #pragma unroll
    for (int off = 1; off < 64; off <<= 1) {
        int w = __shfl_up(incl, off);
        if (lane >= off) incl += w;
    }
    __shared__ int wtot[16];
    if (lane == 63) wtot[wave] = incl;
    __syncthreads();
    int woff = 0;
    for (int i = 0; i < wave; ++i) woff += wtot[i];
    if (idx < M) offs[idx] = bsum[blockIdx.x] + woff + incl - v;
}

// ---- 3. scatter packed entries using LDS cursors (int4 edge loads)
__global__ __launch_bounds__(1024) void bin_scatter(const int* __restrict__ esrc,
                                                    const int* __restrict__ edst,
                                                    const int* __restrict__ offs,
                                                    int* __restrict__ binned,
                                                    int E, int B) {
    __shared__ int lcur[1024];
    int tid = threadIdx.x, blk = blockIdx.x;
    for (int b = tid; b < B; b += 1024) lcur[b] = offs[b * NBLK + blk];
    __syncthreads();
    int chunk = chunk_of(E);
    int start = blk * chunk;
    int end = min(E, start + chunk);
    int v4s = start >> 2, v4e = end >> 2;
    for (int i = v4s + tid; i < v4e; i += 1024) {
        int4 d = ((const int4*)edst)[i];
        int4 s = ((const int4*)esrc)[i];
        int p0 = atomicAdd(&lcur[d.x >> RLOG], 1);
        int p1 = atomicAdd(&lcur[d.y >> RLOG], 1);
        int p2 = atomicAdd(&lcur[d.z >> RLOG], 1);
        int p3 = atomicAdd(&lcur[d.w >> RLOG], 1);
        binned[p0] = ((d.x & (RNODES - 1)) << 17) | s.x;
        binned[p1] = ((d.y & (RNODES - 1)) << 17) | s.y;
        binned[p2] = ((d.z & (RNODES - 1)) << 17) | s.z;
        binned[p3] = ((d.w & (RNODES - 1)) << 17) | s.w;
    }
    for (int i = (v4e << 2) + tid; i < end; i += 1024) {
        int d = edst[i];
        int s = esrc[i];
        int pos = atomicAdd(&lcur[d >> RLOG], 1);
        binned[pos] = ((d & (RNODES - 1)) << 17) | s;
    }
}

// ---- 4. in-place node sort within each bucket
__global__ __launch_bounds__(256) void node_sort(int* __restrict__ binned,
                                                 const int* __restrict__ offs,
                                                 int* __restrict__ nodestart,
                                                 int* __restrict__ degarr,
                                                 int E, int N, int B) {
    __shared__ int sl[CAP];
    __shared__ int c128[RNODES];
    __shared__ int pos[RNODES];
    int tid = threadIdx.x;
    int b = blockIdx.x;
    int start = offs[b * NBLK];
    int end = (b + 1 < B) ? offs[(b + 1) * NBLK] : E;
    int m = min(end - start, CAP);

    for (int i = tid; i < m; i += 256) sl[i] = binned[start + i];
    if (tid < RNODES) c128[tid] = 0;
    __syncthreads();
    for (int i = tid; i < m; i += 256) atomicAdd(&c128[sl[i] >> 17], 1);
    __syncthreads();

    int x = 0, incl = 0;
    if (tid < RNODES) { x = c128[tid]; incl = x; }
    #pragma unroll
    for (int off = 1; off < RNODES; off <<= 1) {
        int y = 0;
        if (tid < RNODES && tid >= off) y = c128[tid - off];
        __syncthreads();
        if (tid < RNODES) { incl += y; c128[tid] = incl; }
        __syncthreads();
    }
    if (tid < RNODES) {
        int excl = incl - x;
        pos[tid] = excl;
        int node = b * RNODES + tid;
        if (node < N) {
            nodestart[node] = start + excl;
            degarr[node] = x;
        }
    }
    __syncthreads();
    for (int i = tid; i < m; i += 256) {
        int e = sl[i];
        int p = atomicAdd(&pos[e >> 17], 1);
        binned[start + p] = e & 131071;
    }
}

// ---- 5. gather: one wave per node, writes nbr_mean as bf16 into xnbr
__global__ __launch_bounds__(256) void gather_kernel(
    const float* __restrict__ intensity, const int* __restrict__ binned,
    const int* __restrict__ nodestart, const int* __restrict__ degarr,
    unsigned short* __restrict__ xnbr, int N) {
    int lane = threadIdx.x & 63;
    int wave = threadIdx.x >> 6;
    int gid = lane >> 3;
    int fl = lane & 7;
    int gwave = blockIdx.x * 4 + wave;
    int wstride = gridDim.x * 4;
    for (int n = gwave; n < N; n += wstride) {
        int st = nodestart[n];
        int dg = degarr[n];
        float4 a = make_float4(0.f, 0.f, 0.f, 0.f);
        int j = gid;
        for (; j + 8 < dg; j += 16) {
            int s0 = binned[st + j];
            int s1 = binned[st + j + 8];
            float4 v0 = ((const float4*)intensity)[(size_t)s0 * 8 + fl];
            float4 v1 = ((const float4*)intensity)[(size_t)s1 * 8 + fl];
            a.x += v0.x + v1.x; a.y += v0.y + v1.y;
            a.z += v0.z + v1.z; a.w += v0.w + v1.w;
        }
        if (j < dg) {
            int s0 = binned[st + j];
            float4 v0 = ((const float4*)intensity)[(size_t)s0 * 8 + fl];
            a.x += v0.x; a.y += v0.y; a.z += v0.z; a.w += v0.w;
        }
        #pragma unroll
        for (int off = 8; off < 64; off <<= 1) {
            a.x += __shfl_xor(a.x, off);
            a.y += __shfl_xor(a.y, off);
            a.z += __shfl_xor(a.z, off);
            a.w += __shfl_xor(a.w, off);
        }
        if (lane < 8) {
            float inv = (dg > 0) ? 1.0f / (float)dg : 0.0f;
            ushort4 r;
            r.x = f2bf(a.x * inv); r.y = f2bf(a.y * inv);
            r.z = f2bf(a.z * inv); r.w = f2bf(a.w * inv);
            *(ushort4*)(xnbr + (size_t)n * 32 + fl * 4) = r;
        }
    }
}

// ---- 6. build stacked bf16 weight matrix Wbig[192][64]
__global__ __launch_bounds__(256) void prep_w(const float* __restrict__ Wf,
                                              const float* __restrict__ Wg,
                                              const float* __restrict__ Wz,
                                              const float* __restrict__ WA,
                                              unsigned short* __restrict__ wbig) {
    int idx = blockIdx.x * 256 + threadIdx.x;
    if (idx >= 192 * 64) return;
    int r = idx >> 6, k = idx & 63;
    float v = (r < 64)  ? Wf[r * 64 + k]
            : (r < 128) ? Wg[(r - 64) * 64 + k]
            : (r < 160) ? Wz[(r - 128) * 64 + k]
                        : WA[(r - 160) * 64 + k];
    wbig[idx] = f2bf(v);
}

// ---- 7. MFMA node kernel: one wave = 16 nodes, 12 feature-tiles x K=64
#define HPAD 194
__global__ __launch_bounds__(256, 3) void node_mfma(
    const float* __restrict__ u, const float* __restrict__ intensity,
    const unsigned short* __restrict__ xnbr,
    const unsigned short* __restrict__ wbig,
    const float* __restrict__ bfp, const float* __restrict__ bgp,
    const float* __restrict__ bzp, const float* __restrict__ bAp,
    float* __restrict__ out, int N) {
    __shared__ float Hlds[4][16 * HPAD];
    int tid = threadIdx.x;
    int lane = tid & 63;
    int wave = tid >> 6;
    int tile = blockIdx.x * 4 + wave;
    int ntiles = N >> 4;
    if (tile >= ntiles) return;

    int col = lane & 15;
    int kg = lane >> 4;
    int n0 = tile * 16;
    int node = n0 + col;

    const float* ub = u + (size_t)node * 64 + kg * 8;
    float4 u0 = *(const float4*)(ub);
    float4 u1 = *(const float4*)(ub + 4);
    float4 u2 = *(const float4*)(ub + 32);
    float4 u3 = *(const float4*)(ub + 36);
    const float* ib = intensity + (size_t)node * 32 + kg * 8;
    float4 i0 = *(const float4*)(ib);
    float4 i1 = *(const float4*)(ib + 4);
    short8 au0, au1, ax0;
    au0[0]=(short)f2bf(u0.x); au0[1]=(short)f2bf(u0.y); au0[2]=(short)f2bf(u0.z); au0[3]=(short)f2bf(u0.w);
    au0[4]=(short)f2bf(u1.x); au0[5]=(short)f2bf(u1.y); au0[6]=(short)f2bf(u1.z); au0[7]=(short)f2bf(u1.w);
    au1[0]=(short)f2bf(u2.x); au1[1]=(short)f2bf(u2.y); au1[2]=(short)f2bf(u2.z); au1[3]=(short)f2bf(u2.w);
    au1[4]=(short)f2bf(u3.x); au1[5]=(short)f2bf(u3.y); au1[6]=(short)f2bf(u3.z); au1[7]=(short)f2bf(u3.w);
    ax0[0]=(short)f2bf(i0.x); ax0[1]=(short)f2bf(i0.y); ax0[2]=(short)f2bf(i0.z); ax0[3]=(short)f2bf(i0.w);
    ax0[4]=(short)f2bf(i1.x); ax0[5]=(short)f2bf(i1.y); ax0[6]=(short)f2bf(i1.z); ax0[7]=(short)f2bf(i1.w);
    short8 ax1 = *(const short8*)(xnbr + (size_t)node * 32 + kg * 8);

    const short8* wb = (const short8*)wbig;
    f32x4 acc[12];
    #pragma unroll
    for (int t = 0; t < 12; ++t) acc[t] = (f32x4){0.f, 0.f, 0.f, 0.f};
    #pragma unroll
    for (int t = 0; t < 12; ++t) {
        short8 a0 = (t < 10) ? au0 : ax0;
        short8 a1 = (t < 10) ? au1 : ax1;
        short8 b0 = wb[(t * 16 + col) * 8 + kg];
        short8 b1 = wb[(t * 16 + col) * 8 + 4 + kg];
        acc[t] = __builtin_amdgcn_mfma_f32_16x16x32_bf16(a0, b0, acc[t], 0, 0, 0);
        acc[t] = __builtin_amdgcn_mfma_f32_16x16x32_bf16(a1, b1, acc[t], 0, 0, 0);
    }

    float* H = Hlds[wave];
    #pragma unroll
    for (int t = 0; t < 12; ++t) {
        #pragma unroll
        for (int r = 0; r < 4; ++r)
            H[(kg * 4 + r) * HPAD + t * 16 + col] = acc[t][r];
    }

    float bfv = bfp[lane];
    float bgv = bgp[lane];
    float bzv = (lane < 32) ? bzp[lane] : bAp[lane - 32];
    #pragma unroll 4
    for (int nl = 0; nl < 16; ++nl) {
        int nd = n0 + nl;
        float fpre = H[nl * HPAD + lane] + bfv;
        float gpre = H[nl * HPAD + 64 + lane] + bgv;
        float zpre = H[nl * HPAD + 128 + lane] + bzv;
        float uval = u[(size_t)nd * 64 + lane];
        float Fu = softplus_fast(fpre);
        float Gu = softplus_fast(gpre);
        float zv = (lane < 32) ? tanh_fast(zpre) : fmaxf(zpre, 0.0f);
        float du = -Fu * uval + Gu * zv;
        float a = du * uval;
        float b = uval * uval;
        #pragma unroll
        for (int off = 16; off; off >>= 1) {
            a += __shfl_xor(a, off);
            b += __shfl_xor(b, off);
        }
        float res = (lane < 32) ? (du - a * __builtin_amdgcn_rcpf(b) * uval) : du;
        out[(size_t)nd * 64 + lane] = res;
    }
}

extern "C" void kernel_launch(void* const* d_in, const int* in_sizes, int n_in,
                              void* d_out, int out_size, void* d_ws, size_t ws_size,
                              hipStream_t stream) {
    const float* u         = (const float*)d_in[0];
    const float* intensity = (const float*)d_in[1];
    const int*   esrc      = (const int*)d_in[2];
    const int*   edst      = (const int*)d_in[3];
    const float* Wf        = (const float*)d_in[4];
    const float* bf        = (const float*)d_in[5];
    const float* Wg        = (const float*)d_in[6];
    const float* bg        = (const float*)d_in[7];
    const float* Wz        = (const float*)d_in[8];
    const float* bz        = (const float*)d_in[9];
    const float* WA        = (const float*)d_in[10];
    const float* bA        = (const float*)d_in[11];

    int N = in_sizes[0] / 64;
    int E = in_sizes[2];
    int B = (N + RNODES - 1) / RNODES;          // 782
    int M = B * NBLK;                            // 200192
    int nb = (M + 1023) / 1024;                  // 196 (<=1024)

    int* cnt       = (int*)d_ws;                 // M
    int* offs      = cnt + M;                    // M
    int* bsum      = offs + M;                   // 1024
    int* binned    = bsum + 1024;                // E
    int* nodestart = binned + E;                 // N
    int* degarr    = nodestart + N;              // N
    unsigned short* xnbr = (unsigned short*)(degarr + N);   // N*32
    unsigned short* wbig = xnbr + (size_t)N * 32;           // 192*64

    prep_w<<<48, 256, 0, stream>>>(Wf, Wg, Wz, WA, wbig);
    bin_count<<<NBLK, 1024, 0, stream>>>(edst, cnt, E, B);
    scan_reduce<<<nb, 1024, 0, stream>>>(cnt, bsum, M);
    scan_top<<<1, 1024, 0, stream>>>(bsum, nb);
    scan_final<<<nb, 1024, 0, stream>>>(cnt, bsum, offs, M);
    bin_scatter<<<NBLK, 1024, 0, stream>>>(esrc, edst, offs, binned, E, B);
    node_sort<<<B, 256, 0, stream>>>(binned, offs, nodestart, degarr, E, N, B);
    gather_kernel<<<2048, 256, 0, stream>>>(intensity, binned, nodestart, degarr,
                                            xnbr, N);
    int ntiles = N / 16;
    int nblocks = (ntiles + 3) / 4;
    node_mfma<<<nblocks, 256, 0, stream>>>(u, intensity, xnbr, wbig,
                                           bf, bg, bz, bA, (float*)d_out, N);
}

// Round 9
// 156.474 us; speedup vs baseline: 5.6701x; 1.0231x over previous
//
#include <hip/hip_runtime.h>

// N=100000 nodes, D=64, P=Q=32, E=3200000 edges.
// Pipeline: intensity->bf16 copy -> bucket partition (radix by dst>>7, 256
// blocks, int4 loads) -> in-place node sort -> per-node CSR gather on bf16
// rows (64B, 8 lanes/edge, unroll 4) -> MFMA node kernel (bf16 16x16x32).

#define RLOG 7
#define RNODES 128
#define NBLK 256
#define CAP 6144

typedef __attribute__((ext_vector_type(8))) short short8;
typedef __attribute__((ext_vector_type(4))) float f32x4;

__device__ __forceinline__ unsigned short f2bf(float x) {
    union { float f; unsigned u; } v; v.f = x;
    unsigned r = v.u + 0x7FFF + ((v.u >> 16) & 1);  // RNE
    return (unsigned short)(r >> 16);
}

__device__ __forceinline__ float bf2f(unsigned short b) {
    union { unsigned u; float f; } v; v.u = ((unsigned)b) << 16;
    return v.f;
}

__device__ __forceinline__ float softplus_fast(float x) {
    float t = __expf(-fabsf(x));
    return fmaxf(x, 0.0f) + __logf(1.0f + t);
}

__device__ __forceinline__ float tanh_fast(float x) {
    float t = __expf(-2.0f * fabsf(x));
    float m = (1.0f - t) * __builtin_amdgcn_rcpf(1.0f + t);
    return __builtin_copysignf(m, x);
}

__device__ __forceinline__ int chunk_of(int E) {
    return (((E + NBLK - 1) / NBLK) + 3) & ~3;
}

// ---- 0. intensity -> bf16 copy
__global__ __launch_bounds__(256) void cvt_int(const float* __restrict__ x,
                                               unsigned short* __restrict__ y,
                                               int total4) {
    int t0 = blockIdx.x * 256 + threadIdx.x;
    int stride = gridDim.x * 256;
    for (int i = t0; i < total4; i += stride) {
        float4 v = ((const float4*)x)[i];
        ushort4 r;
        r.x = f2bf(v.x); r.y = f2bf(v.y); r.z = f2bf(v.z); r.w = f2bf(v.w);
        ((ushort4*)y)[i] = r;
    }
}

// ---- 1. per-block bucket histogram: cnt[b*NBLK + blk]
__global__ __launch_bounds__(1024) void bin_count(const int* __restrict__ edst,
                                                  int* __restrict__ cnt,
                                                  int E, int B) {
    __shared__ int lcnt[1024];
    int tid = threadIdx.x, blk = blockIdx.x;
    for (int b = tid; b < B; b += 1024) lcnt[b] = 0;
    __syncthreads();
    int chunk = chunk_of(E);
    int start = blk * chunk;
    int end = min(E, start + chunk);
    int v4s = start >> 2, v4e = end >> 2;
    for (int i = v4s + tid; i < v4e; i += 1024) {
        int4 d = ((const int4*)edst)[i];
        atomicAdd(&lcnt[d.x >> RLOG], 1);
        atomicAdd(&lcnt[d.y >> RLOG], 1);
        atomicAdd(&lcnt[d.z >> RLOG], 1);
        atomicAdd(&lcnt[d.w >> RLOG], 1);
    }
    for (int i = (v4e << 2) + tid; i < end; i += 1024)
        atomicAdd(&lcnt[edst[i] >> RLOG], 1);
    __syncthreads();
    for (int b = tid; b < B; b += 1024) cnt[b * NBLK + blk] = lcnt[b];
}

// ---- 2a. per-block partial sums
__global__ __launch_bounds__(1024) void scan_reduce(const int* __restrict__ cnt,
                                                    int* __restrict__ bsum, int M) {
    int idx = blockIdx.x * 1024 + threadIdx.x;
    int v = (idx < M) ? cnt[idx] : 0;
    #pragma unroll
    for (int off = 32; off; off >>= 1) v += __shfl_xor(v, off);
    __shared__ int wtot[16];
    int lane = threadIdx.x & 63, wave = threadIdx.x >> 6;
    if (lane == 0) wtot[wave] = v;
    __syncthreads();
    if (threadIdx.x == 0) {
        int s = 0;
        #pragma unroll
        for (int i = 0; i < 16; ++i) s += wtot[i];
        bsum[blockIdx.x] = s;
    }
}

// ---- 2b. exclusive scan of block sums (single block, nb <= 1024)
__global__ __launch_bounds__(1024) void scan_top(int* __restrict__ bsum, int nb) {
    int t = threadIdx.x;
    int lane = t & 63, wave = t >> 6;
    int v = (t < nb) ? bsum[t] : 0;
    int incl = v;
    #pragma unroll
    for (int off = 1; off < 64; off <<= 1) {
        int w = __shfl_up(incl, off);
        if (lane >= off) incl += w;
    }
    __shared__ int wt[16];
    if (lane == 63) wt[wave] = incl;
    __syncthreads();
    int woff = 0;
    for (int i = 0; i < wave; ++i) woff += wt[i];
    if (t < nb) bsum[t] = woff + incl - v;
}

// ---- 2c. final exclusive scan -> offs
__global__ __launch_bounds__(1024) void scan_final(const int* __restrict__ cnt,
                                                   const int* __restrict__ bsum,
                                                   int* __restrict__ offs, int M) {
    int t = threadIdx.x;
    int idx = blockIdx.x * 1024 + t;
    int lane = t & 63, wave = t >> 6;
    int v = (idx < M) ? cnt[idx] : 0;
    int incl = v;
    #pragma unroll
    for (int off = 1; off < 64; off <<= 1) {
        int w = __shfl_up(incl, off);
        if (lane >= off) incl += w;
    }
    __shared__ int wtot[16];
    if (lane == 63) wtot[wave] = incl;
    __syncthreads();
    int woff = 0;
    for (int i = 0; i < wave; ++i) woff += wtot[i];
    if (idx < M) offs[idx] = bsum[blockIdx.x] + woff + incl - v;
}

// ---- 3. scatter packed entries using LDS cursors (int4 edge loads)
__global__ __launch_bounds__(1024) void bin_scatter(const int* __restrict__ esrc,
                                                    const int* __restrict__ edst,
                                                    const int* __restrict__ offs,
                                                    int* __restrict__ binned,
                                                    int E, int B) {
    __shared__ int lcur[1024];
    int tid = threadIdx.x, blk = blockIdx.x;
    for (int b = tid; b < B; b += 1024) lcur[b] = offs[b * NBLK + blk];
    __syncthreads();
    int chunk = chunk_of(E);
    int start = blk * chunk;
    int end = min(E, start + chunk);
    int v4s = start >> 2, v4e = end >> 2;
    for (int i = v4s + tid; i < v4e; i += 1024) {
        int4 d = ((const int4*)edst)[i];
        int4 s = ((const int4*)esrc)[i];
        int p0 = atomicAdd(&lcur[d.x >> RLOG], 1);
        int p1 = atomicAdd(&lcur[d.y >> RLOG], 1);
        int p2 = atomicAdd(&lcur[d.z >> RLOG], 1);
        int p3 = atomicAdd(&lcur[d.w >> RLOG], 1);
        binned[p0] = ((d.x & (RNODES - 1)) << 17) | s.x;
        binned[p1] = ((d.y & (RNODES - 1)) << 17) | s.y;
        binned[p2] = ((d.z & (RNODES - 1)) << 17) | s.z;
        binned[p3] = ((d.w & (RNODES - 1)) << 17) | s.w;
    }
    for (int i = (v4e << 2) + tid; i < end; i += 1024) {
        int d = edst[i];
        int s = esrc[i];
        int pos = atomicAdd(&lcur[d >> RLOG], 1);
        binned[pos] = ((d & (RNODES - 1)) << 17) | s;
    }
}

// ---- 4. in-place node sort within each bucket
__global__ __launch_bounds__(256) void node_sort(int* __restrict__ binned,
                                                 const int* __restrict__ offs,
                                                 int* __restrict__ nodestart,
                                                 int* __restrict__ degarr,
                                                 int E, int N, int B) {
    __shared__ int sl[CAP];
    __shared__ int c128[RNODES];
    __shared__ int pos[RNODES];
    int tid = threadIdx.x;
    int b = blockIdx.x;
    int start = offs[b * NBLK];
    int end = (b + 1 < B) ? offs[(b + 1) * NBLK] : E;
    int m = min(end - start, CAP);

    for (int i = tid; i < m; i += 256) sl[i] = binned[start + i];
    if (tid < RNODES) c128[tid] = 0;
    __syncthreads();
    for (int i = tid; i < m; i += 256) atomicAdd(&c128[sl[i] >> 17], 1);
    __syncthreads();

    int x = 0, incl = 0;
    if (tid < RNODES) { x = c128[tid]; incl = x; }
    #pragma unroll
    for (int off = 1; off < RNODES; off <<= 1) {
        int y = 0;
        if (tid < RNODES && tid >= off) y = c128[tid - off];
        __syncthreads();
        if (tid < RNODES) { incl += y; c128[tid] = incl; }
        __syncthreads();
    }
    if (tid < RNODES) {
        int excl = incl - x;
        pos[tid] = excl;
        int node = b * RNODES + tid;
        if (node < N) {
            nodestart[node] = start + excl;
            degarr[node] = x;
        }
    }
    __syncthreads();
    for (int i = tid; i < m; i += 256) {
        int e = sl[i];
        int p = atomicAdd(&pos[e >> 17], 1);
        binned[start + p] = e & 131071;
    }
}

// ---- 5. gather on bf16 rows: one wave per node, 8 lanes/edge, unroll 4
__global__ __launch_bounds__(256) void gather_kernel(
    const unsigned short* __restrict__ ibf, const int* __restrict__ binned,
    const int* __restrict__ nodestart, const int* __restrict__ degarr,
    unsigned short* __restrict__ xnbr, int N) {
    int lane = threadIdx.x & 63;
    int wave = threadIdx.x >> 6;
    int gid = lane >> 3;       // 8 groups of 8 lanes
    int fl = lane & 7;         // ushort4 index within the 32-feature row
    int gwave = blockIdx.x * 4 + wave;
    int wstride = gridDim.x * 4;
    for (int n = gwave; n < N; n += wstride) {
        int st = nodestart[n];
        int dg = degarr[n];
        float a0 = 0.f, a1 = 0.f, a2 = 0.f, a3 = 0.f;
        int j = gid;
        for (; j + 24 < dg; j += 32) {
            int s0 = binned[st + j];
            int s1 = binned[st + j + 8];
            int s2 = binned[st + j + 16];
            int s3 = binned[st + j + 24];
            ushort4 v0 = ((const ushort4*)ibf)[(size_t)s0 * 8 + fl];
            ushort4 v1 = ((const ushort4*)ibf)[(size_t)s1 * 8 + fl];
            ushort4 v2 = ((const ushort4*)ibf)[(size_t)s2 * 8 + fl];
            ushort4 v3 = ((const ushort4*)ibf)[(size_t)s3 * 8 + fl];
            a0 += bf2f(v0.x) + bf2f(v1.x) + bf2f(v2.x) + bf2f(v3.x);
            a1 += bf2f(v0.y) + bf2f(v1.y) + bf2f(v2.y) + bf2f(v3.y);
            a2 += bf2f(v0.z) + bf2f(v1.z) + bf2f(v2.z) + bf2f(v3.z);
            a3 += bf2f(v0.w) + bf2f(v1.w) + bf2f(v2.w) + bf2f(v3.w);
        }
        for (; j < dg; j += 8) {
            int s0 = binned[st + j];
            ushort4 v0 = ((const ushort4*)ibf)[(size_t)s0 * 8 + fl];
            a0 += bf2f(v0.x); a1 += bf2f(v0.y); a2 += bf2f(v0.z); a3 += bf2f(v0.w);
        }
        #pragma unroll
        for (int off = 8; off < 64; off <<= 1) {
            a0 += __shfl_xor(a0, off);
            a1 += __shfl_xor(a1, off);
            a2 += __shfl_xor(a2, off);
            a3 += __shfl_xor(a3, off);
        }
        if (lane < 8) {
            float inv = (dg > 0) ? 1.0f / (float)dg : 0.0f;
            ushort4 r;
            r.x = f2bf(a0 * inv); r.y = f2bf(a1 * inv);
            r.z = f2bf(a2 * inv); r.w = f2bf(a3 * inv);
            ((ushort4*)xnbr)[(size_t)n * 8 + fl] = r;
        }
    }
}

// ---- 6. build stacked bf16 weight matrix Wbig[192][64]
__global__ __launch_bounds__(256) void prep_w(const float* __restrict__ Wf,
                                              const float* __restrict__ Wg,
                                              const float* __restrict__ Wz,
                                              const float* __restrict__ WA,
                                              unsigned short* __restrict__ wbig) {
    int idx = blockIdx.x * 256 + threadIdx.x;
    if (idx >= 192 * 64) return;
    int r = idx >> 6, k = idx & 63;
    float v = (r < 64)  ? Wf[r * 64 + k]
            : (r < 128) ? Wg[(r - 64) * 64 + k]
            : (r < 160) ? Wz[(r - 128) * 64 + k]
                        : WA[(r - 160) * 64 + k];
    wbig[idx] = f2bf(v);
}

// ---- 7. MFMA node kernel: one wave = 16 nodes, 12 feature-tiles x K=64
#define HPAD 194
__global__ __launch_bounds__(256, 3) void node_mfma(
    const float* __restrict__ u,
    const unsigned short* __restrict__ ibf,
    const unsigned short* __restrict__ xnbr,
    const unsigned short* __restrict__ wbig,
    const float* __restrict__ bfp, const float* __restrict__ bgp,
    const float* __restrict__ bzp, const float* __restrict__ bAp,
    float* __restrict__ out, int N) {
    __shared__ float Hlds[4][16 * HPAD];
    int tid = threadIdx.x;
    int lane = tid & 63;
    int wave = tid >> 6;
    int tile = blockIdx.x * 4 + wave;
    int ntiles = N >> 4;
    if (tile >= ntiles) return;

    int col = lane & 15;
    int kg = lane >> 4;
    int n0 = tile * 16;
    int node = n0 + col;

    const float* ub = u + (size_t)node * 64 + kg * 8;
    float4 u0 = *(const float4*)(ub);
    float4 u1 = *(const float4*)(ub + 4);
    float4 u2 = *(const float4*)(ub + 32);
    float4 u3 = *(const float4*)(ub + 36);
    short8 au0, au1;
    au0[0]=(short)f2bf(u0.x); au0[1]=(short)f2bf(u0.y); au0[2]=(short)f2bf(u0.z); au0[3]=(short)f2bf(u0.w);
    au0[4]=(short)f2bf(u1.x); au0[5]=(short)f2bf(u1.y); au0[6]=(short)f2bf(u1.z); au0[7]=(short)f2bf(u1.w);
    au1[0]=(short)f2bf(u2.x); au1[1]=(short)f2bf(u2.y); au1[2]=(short)f2bf(u2.z); au1[3]=(short)f2bf(u2.w);
    au1[4]=(short)f2bf(u3.x); au1[5]=(short)f2bf(u3.y); au1[6]=(short)f2bf(u3.z); au1[7]=(short)f2bf(u3.w);
    short8 ax0 = *(const short8*)(ibf  + (size_t)node * 32 + kg * 8);
    short8 ax1 = *(const short8*)(xnbr + (size_t)node * 32 + kg * 8);

    const short8* wb = (const short8*)wbig;
    f32x4 acc[12];
    #pragma unroll
    for (int t = 0; t < 12; ++t) acc[t] = (f32x4){0.f, 0.f, 0.f, 0.f};
    #pragma unroll
    for (int t = 0; t < 12; ++t) {
        short8 a0 = (t < 10) ? au0 : ax0;
        short8 a1 = (t < 10) ? au1 : ax1;
        short8 b0 = wb[(t * 16 + col) * 8 + kg];
        short8 b1 = wb[(t * 16 + col) * 8 + 4 + kg];
        acc[t] = __builtin_amdgcn_mfma_f32_16x16x32_bf16(a0, b0, acc[t], 0, 0, 0);
        acc[t] = __builtin_amdgcn_mfma_f32_16x16x32_bf16(a1, b1, acc[t], 0, 0, 0);
    }

    float* H = Hlds[wave];
    #pragma unroll
    for (int t = 0; t < 12; ++t) {
        #pragma unroll
        for (int r = 0; r < 4; ++r)
            H[(kg * 4 + r) * HPAD + t * 16 + col] = acc[t][r];
    }

    float bfv = bfp[lane];
    float bgv = bgp[lane];
    float bzv = (lane < 32) ? bzp[lane] : bAp[lane - 32];
    #pragma unroll 4
    for (int nl = 0; nl < 16; ++nl) {
        int nd = n0 + nl;
        float fpre = H[nl * HPAD + lane] + bfv;
        float gpre = H[nl * HPAD + 64 + lane] + bgv;
        float zpre = H[nl * HPAD + 128 + lane] + bzv;
        float uval = u[(size_t)nd * 64 + lane];
        float Fu = softplus_fast(fpre);
        float Gu = softplus_fast(gpre);
        float zv = (lane < 32) ? tanh_fast(zpre) : fmaxf(zpre, 0.0f);
        float du = -Fu * uval + Gu * zv;
        float a = du * uval;
        float b = uval * uval;
        #pragma unroll
        for (int off = 16; off; off >>= 1) {
            a += __shfl_xor(a, off);
            b += __shfl_xor(b, off);
        }
        float res = (lane < 32) ? (du - a * __builtin_amdgcn_rcpf(b) * uval) : du;
        out[(size_t)nd * 64 + lane] = res;
    }
}

extern "C" void kernel_launch(void* const* d_in, const int* in_sizes, int n_in,
                              void* d_out, int out_size, void* d_ws, size_t ws_size,
                              hipStream_t stream) {
    const float* u         = (const float*)d_in[0];
    const float* intensity = (const float*)d_in[1];
    const int*   esrc      = (const int*)d_in[2];
    const int*   edst      = (const int*)d_in[3];
    const float* Wf        = (const float*)d_in[4];
    const float* bf        = (const float*)d_in[5];
    const float* Wg        = (const float*)d_in[6];
    const float* bg        = (const float*)d_in[7];
    const float* Wz        = (const float*)d_in[8];
    const float* bz        = (const float*)d_in[9];
    const float* WA        = (const float*)d_in[10];
    const float* bA        = (const float*)d_in[11];

    int N = in_sizes[0] / 64;
    int E = in_sizes[2];
    int B = (N + RNODES - 1) / RNODES;          // 782
    int M = B * NBLK;                            // 200192
    int nb = (M + 1023) / 1024;                  // 196

    int* cnt       = (int*)d_ws;                 // M
    int* offs      = cnt + M;                    // M
    int* bsum      = offs + M;                   // 1024
    int* binned    = bsum + 1024;                // E
    int* nodestart = binned + E;                 // N
    int* degarr    = nodestart + N;              // N
    unsigned short* xnbr = (unsigned short*)(degarr + N);   // N*32
    unsigned short* wbig = xnbr + (size_t)N * 32;           // 192*64
    unsigned short* ibf  = wbig + 192 * 64;                 // N*32

    cvt_int<<<2048, 256, 0, stream>>>(intensity, ibf, N * 8);
    prep_w<<<48, 256, 0, stream>>>(Wf, Wg, Wz, WA, wbig);
    bin_count<<<NBLK, 1024, 0, stream>>>(edst, cnt, E, B);
    scan_reduce<<<nb, 1024, 0, stream>>>(cnt, bsum, M);
    scan_top<<<1, 1024, 0, stream>>>(bsum, nb);
    scan_final<<<nb, 1024, 0, stream>>>(cnt, bsum, offs, M);
    bin_scatter<<<NBLK, 1024, 0, stream>>>(esrc, edst, offs, binned, E, B);
    node_sort<<<B, 256, 0, stream>>>(binned, offs, nodestart, degarr, E, N, B);
    gather_kernel<<<2048, 256, 0, stream>>>(ibf, binned, nodestart, degarr,
                                            xnbr, N);
    int ntiles = N / 16;
    int nblocks = (ntiles + 3) / 4;
    node_mfma<<<nblocks, 256, 0, stream>>>(u, ibf, xnbr, wbig,
                                           bf, bg, bz, bA, (float*)d_out, N);
}

// Round 10
// 144.571 us; speedup vs baseline: 6.1370x; 1.0823x over previous
//
#include <hip/hip_runtime.h>

// N=100000 nodes, D=64, P=Q=32, E=3200000 edges.
// Pipeline: intensity->bf16 copy -> bucket partition (radix by dst>>7) ->
// in-place node sort -> per-node CSR gather on bf16 rows -> MFMA node kernel
// with epilogue computed directly in D-fragment layout (zero LDS).

#define RLOG 7
#define RNODES 128
#define NBLK 256
#define CAP 6144

typedef __attribute__((ext_vector_type(8))) short short8;
typedef __attribute__((ext_vector_type(4))) float f32x4;

__device__ __forceinline__ unsigned short f2bf(float x) {
    union { float f; unsigned u; } v; v.f = x;
    unsigned r = v.u + 0x7FFF + ((v.u >> 16) & 1);  // RNE
    return (unsigned short)(r >> 16);
}

__device__ __forceinline__ float bf2f(unsigned short b) {
    union { unsigned u; float f; } v; v.u = ((unsigned)b) << 16;
    return v.f;
}

__device__ __forceinline__ float softplus_fast(float x) {
    float t = __expf(-fabsf(x));
    return fmaxf(x, 0.0f) + __logf(1.0f + t);
}

__device__ __forceinline__ float tanh_fast(float x) {
    float t = __expf(-2.0f * fabsf(x));
    float m = (1.0f - t) * __builtin_amdgcn_rcpf(1.0f + t);
    return __builtin_copysignf(m, x);
}

__device__ __forceinline__ int chunk_of(int E) {
    return (((E + NBLK - 1) / NBLK) + 3) & ~3;
}

// ---- 0. intensity -> bf16 copy
__global__ __launch_bounds__(256) void cvt_int(const float* __restrict__ x,
                                               unsigned short* __restrict__ y,
                                               int total4) {
    int t0 = blockIdx.x * 256 + threadIdx.x;
    int stride = gridDim.x * 256;
    for (int i = t0; i < total4; i += stride) {
        float4 v = ((const float4*)x)[i];
        ushort4 r;
        r.x = f2bf(v.x); r.y = f2bf(v.y); r.z = f2bf(v.z); r.w = f2bf(v.w);
        ((ushort4*)y)[i] = r;
    }
}

// ---- 1. per-block bucket histogram: cnt[b*NBLK + blk]
__global__ __launch_bounds__(1024) void bin_count(const int* __restrict__ edst,
                                                  int* __restrict__ cnt,
                                                  int E, int B) {
    __shared__ int lcnt[1024];
    int tid = threadIdx.x, blk = blockIdx.x;
    for (int b = tid; b < B; b += 1024) lcnt[b] = 0;
    __syncthreads();
    int chunk = chunk_of(E);
    int start = blk * chunk;
    int end = min(E, start + chunk);
    int v4s = start >> 2, v4e = end >> 2;
    for (int i = v4s + tid; i < v4e; i += 1024) {
        int4 d = ((const int4*)edst)[i];
        atomicAdd(&lcnt[d.x >> RLOG], 1);
        atomicAdd(&lcnt[d.y >> RLOG], 1);
        atomicAdd(&lcnt[d.z >> RLOG], 1);
        atomicAdd(&lcnt[d.w >> RLOG], 1);
    }
    for (int i = (v4e << 2) + tid; i < end; i += 1024)
        atomicAdd(&lcnt[edst[i] >> RLOG], 1);
    __syncthreads();
    for (int b = tid; b < B; b += 1024) cnt[b * NBLK + blk] = lcnt[b];
}

// ---- 2a. per-block partial sums
__global__ __launch_bounds__(1024) void scan_reduce(const int* __restrict__ cnt,
                                                    int* __restrict__ bsum, int M) {
    int idx = blockIdx.x * 1024 + threadIdx.x;
    int v = (idx < M) ? cnt[idx] : 0;
    #pragma unroll
    for (int off = 32; off; off >>= 1) v += __shfl_xor(v, off);
    __shared__ int wtot[16];
    int lane = threadIdx.x & 63, wave = threadIdx.x >> 6;
    if (lane == 0) wtot[wave] = v;
    __syncthreads();
    if (threadIdx.x == 0) {
        int s = 0;
        #pragma unroll
        for (int i = 0; i < 16; ++i) s += wtot[i];
        bsum[blockIdx.x] = s;
    }
}

// ---- 2b. exclusive scan of block sums (single block, nb <= 1024)
__global__ __launch_bounds__(1024) void scan_top(int* __restrict__ bsum, int nb) {
    int t = threadIdx.x;
    int lane = t & 63, wave = t >> 6;
    int v = (t < nb) ? bsum[t] : 0;
    int incl = v;
    #pragma unroll
    for (int off = 1; off < 64; off <<= 1) {
        int w = __shfl_up(incl, off);
        if (lane >= off) incl += w;
    }
    __shared__ int wt[16];
    if (lane == 63) wt[wave] = incl;
    __syncthreads();
    int woff = 0;
    for (int i = 0; i < wave; ++i) woff += wt[i];
    if (t < nb) bsum[t] = woff + incl - v;
}

// ---- 2c. final exclusive scan -> offs
__global__ __launch_bounds__(1024) void scan_final(const int* __restrict__ cnt,
                                                   const int* __restrict__ bsum,
                                                   int* __restrict__ offs, int M) {
    int t = threadIdx.x;
    int idx = blockIdx.x * 1024 + t;
    int lane = t & 63, wave = t >> 6;
    int v = (idx < M) ? cnt[idx] : 0;
    int incl = v;
    #pragma unroll
    for (int off = 1; off < 64; off <<= 1) {
        int w = __shfl_up(incl, off);
        if (lane >= off) incl += w;
    }
    __shared__ int wtot[16];
    if (lane == 63) wtot[wave] = incl;
    __syncthreads();
    int woff = 0;
    for (int i = 0; i < wave; ++i) woff += wtot[i];
    if (idx < M) offs[idx] = bsum[blockIdx.x] + woff + incl - v;
}

// ---- 3. scatter packed entries using LDS cursors (int4 edge loads)
__global__ __launch_bounds__(1024) void bin_scatter(const int* __restrict__ esrc,
                                                    const int* __restrict__ edst,
                                                    const int* __restrict__ offs,
                                                    int* __restrict__ binned,
                                                    int E, int B) {
    __shared__ int lcur[1024];
    int tid = threadIdx.x, blk = blockIdx.x;
    for (int b = tid; b < B; b += 1024) lcur[b] = offs[b * NBLK + blk];
    __syncthreads();
    int chunk = chunk_of(E);
    int start = blk * chunk;
    int end = min(E, start + chunk);
    int v4s = start >> 2, v4e = end >> 2;
    for (int i = v4s + tid; i < v4e; i += 1024) {
        int4 d = ((const int4*)edst)[i];
        int4 s = ((const int4*)esrc)[i];
        int p0 = atomicAdd(&lcur[d.x >> RLOG], 1);
        int p1 = atomicAdd(&lcur[d.y >> RLOG], 1);
        int p2 = atomicAdd(&lcur[d.z >> RLOG], 1);
        int p3 = atomicAdd(&lcur[d.w >> RLOG], 1);
        binned[p0] = ((d.x & (RNODES - 1)) << 17) | s.x;
        binned[p1] = ((d.y & (RNODES - 1)) << 17) | s.y;
        binned[p2] = ((d.z & (RNODES - 1)) << 17) | s.z;
        binned[p3] = ((d.w & (RNODES - 1)) << 17) | s.w;
    }
    for (int i = (v4e << 2) + tid; i < end; i += 1024) {
        int d = edst[i];
        int s = esrc[i];
        int pos = atomicAdd(&lcur[d >> RLOG], 1);
        binned[pos] = ((d & (RNODES - 1)) << 17) | s;
    }
}

// ---- 4. in-place node sort within each bucket
__global__ __launch_bounds__(256) void node_sort(int* __restrict__ binned,
                                                 const int* __restrict__ offs,
                                                 int* __restrict__ nodestart,
                                                 int* __restrict__ degarr,
                                                 int E, int N, int B) {
    __shared__ int sl[CAP];
    __shared__ int c128[RNODES];
    __shared__ int pos[RNODES];
    int tid = threadIdx.x;
    int b = blockIdx.x;
    int start = offs[b * NBLK];
    int end = (b + 1 < B) ? offs[(b + 1) * NBLK] : E;
    int m = min(end - start, CAP);

    for (int i = tid; i < m; i += 256) sl[i] = binned[start + i];
    if (tid < RNODES) c128[tid] = 0;
    __syncthreads();
    for (int i = tid; i < m; i += 256) atomicAdd(&c128[sl[i] >> 17], 1);
    __syncthreads();

    int x = 0, incl = 0;
    if (tid < RNODES) { x = c128[tid]; incl = x; }
    #pragma unroll
    for (int off = 1; off < RNODES; off <<= 1) {
        int y = 0;
        if (tid < RNODES && tid >= off) y = c128[tid - off];
        __syncthreads();
        if (tid < RNODES) { incl += y; c128[tid] = incl; }
        __syncthreads();
    }
    if (tid < RNODES) {
        int excl = incl - x;
        pos[tid] = excl;
        int node = b * RNODES + tid;
        if (node < N) {
            nodestart[node] = start + excl;
            degarr[node] = x;
        }
    }
    __syncthreads();
    for (int i = tid; i < m; i += 256) {
        int e = sl[i];
        int p = atomicAdd(&pos[e >> 17], 1);
        binned[start + p] = e & 131071;
    }
}

// ---- 5. gather on bf16 rows: one wave per node, 8 lanes/edge, unroll 4
__global__ __launch_bounds__(256) void gather_kernel(
    const unsigned short* __restrict__ ibf, const int* __restrict__ binned,
    const int* __restrict__ nodestart, const int* __restrict__ degarr,
    unsigned short* __restrict__ xnbr, int N) {
    int lane = threadIdx.x & 63;
    int wave = threadIdx.x >> 6;
    int gid = lane >> 3;       // 8 groups of 8 lanes
    int fl = lane & 7;         // ushort4 index within the 32-feature row
    int gwave = blockIdx.x * 4 + wave;
    int wstride = gridDim.x * 4;
    for (int n = gwave; n < N; n += wstride) {
        int st = nodestart[n];
        int dg = degarr[n];
        float a0 = 0.f, a1 = 0.f, a2 = 0.f, a3 = 0.f;
        int j = gid;
        for (; j + 24 < dg; j += 32) {
            int s0 = binned[st + j];
            int s1 = binned[st + j + 8];
            int s2 = binned[st + j + 16];
            int s3 = binned[st + j + 24];
            ushort4 v0 = ((const ushort4*)ibf)[(size_t)s0 * 8 + fl];
            ushort4 v1 = ((const ushort4*)ibf)[(size_t)s1 * 8 + fl];
            ushort4 v2 = ((const ushort4*)ibf)[(size_t)s2 * 8 + fl];
            ushort4 v3 = ((const ushort4*)ibf)[(size_t)s3 * 8 + fl];
            a0 += bf2f(v0.x) + bf2f(v1.x) + bf2f(v2.x) + bf2f(v3.x);
            a1 += bf2f(v0.y) + bf2f(v1.y) + bf2f(v2.y) + bf2f(v3.y);
            a2 += bf2f(v0.z) + bf2f(v1.z) + bf2f(v2.z) + bf2f(v3.z);
            a3 += bf2f(v0.w) + bf2f(v1.w) + bf2f(v2.w) + bf2f(v3.w);
        }
        for (; j < dg; j += 8) {
            int s0 = binned[st + j];
            ushort4 v0 = ((const ushort4*)ibf)[(size_t)s0 * 8 + fl];
            a0 += bf2f(v0.x); a1 += bf2f(v0.y); a2 += bf2f(v0.z); a3 += bf2f(v0.w);
        }
        #pragma unroll
        for (int off = 8; off < 64; off <<= 1) {
            a0 += __shfl_xor(a0, off);
            a1 += __shfl_xor(a1, off);
            a2 += __shfl_xor(a2, off);
            a3 += __shfl_xor(a3, off);
        }
        if (lane < 8) {
            float inv = (dg > 0) ? 1.0f / (float)dg : 0.0f;
            ushort4 r;
            r.x = f2bf(a0 * inv); r.y = f2bf(a1 * inv);
            r.z = f2bf(a2 * inv); r.w = f2bf(a3 * inv);
            ((ushort4*)xnbr)[(size_t)n * 8 + fl] = r;
        }
    }
}

// ---- 6. build stacked bf16 weight matrix Wbig[192][64]
__global__ __launch_bounds__(256) void prep_w(const float* __restrict__ Wf,
                                              const float* __restrict__ Wg,
                                              const float* __restrict__ Wz,
                                              const float* __restrict__ WA,
                                              unsigned short* __restrict__ wbig) {
    int idx = blockIdx.x * 256 + threadIdx.x;
    if (idx >= 192 * 64) return;
    int r = idx >> 6, k = idx & 63;
    float v = (r < 64)  ? Wf[r * 64 + k]
            : (r < 128) ? Wg[(r - 64) * 64 + k]
            : (r < 160) ? Wz[(r - 128) * 64 + k]
                        : WA[(r - 160) * 64 + k];
    wbig[idx] = f2bf(v);
}

// ---- 7. MFMA node kernel, zero-LDS epilogue in D-fragment layout.
// Lane (col,kg), acc[t][r] = H[node=kg*4+r][feature=t*16+col].
// Output feature j=s*16+col uses acc[s] (f), acc[4+s] (g), acc[8+s] (z/agg).
__global__ __launch_bounds__(256, 4) void node_mfma(
    const float* __restrict__ u,
    const unsigned short* __restrict__ ibf,
    const unsigned short* __restrict__ xnbr,
    const unsigned short* __restrict__ wbig,
    const float* __restrict__ bfp, const float* __restrict__ bgp,
    const float* __restrict__ bzp, const float* __restrict__ bAp,
    float* __restrict__ out, int N) {
    int tid = threadIdx.x;
    int lane = tid & 63;
    int wave = tid >> 6;
    int tile = blockIdx.x * 4 + wave;
    int ntiles = N >> 4;
    if (tile >= ntiles) return;

    int col = lane & 15;
    int kg = lane >> 4;
    int n0 = tile * 16;
    int node = n0 + col;

    const float* ub = u + (size_t)node * 64 + kg * 8;
    float4 u0 = *(const float4*)(ub);
    float4 u1 = *(const float4*)(ub + 4);
    float4 u2 = *(const float4*)(ub + 32);
    float4 u3 = *(const float4*)(ub + 36);
    short8 au0, au1;
    au0[0]=(short)f2bf(u0.x); au0[1]=(short)f2bf(u0.y); au0[2]=(short)f2bf(u0.z); au0[3]=(short)f2bf(u0.w);
    au0[4]=(short)f2bf(u1.x); au0[5]=(short)f2bf(u1.y); au0[6]=(short)f2bf(u1.z); au0[7]=(short)f2bf(u1.w);
    au1[0]=(short)f2bf(u2.x); au1[1]=(short)f2bf(u2.y); au1[2]=(short)f2bf(u2.z); au1[3]=(short)f2bf(u2.w);
    au1[4]=(short)f2bf(u3.x); au1[5]=(short)f2bf(u3.y); au1[6]=(short)f2bf(u3.z); au1[7]=(short)f2bf(u3.w);
    short8 ax0 = *(const short8*)(ibf  + (size_t)node * 32 + kg * 8);
    short8 ax1 = *(const short8*)(xnbr + (size_t)node * 32 + kg * 8);

    const short8* wb = (const short8*)wbig;
    f32x4 acc[12];
    #pragma unroll
    for (int t = 0; t < 12; ++t) acc[t] = (f32x4){0.f, 0.f, 0.f, 0.f};
    #pragma unroll
    for (int t = 0; t < 12; ++t) {
        short8 a0 = (t < 10) ? au0 : ax0;
        short8 a1 = (t < 10) ? au1 : ax1;
        short8 b0 = wb[(t * 16 + col) * 8 + kg];
        short8 b1 = wb[(t * 16 + col) * 8 + 4 + kg];
        acc[t] = __builtin_amdgcn_mfma_f32_16x16x32_bf16(a0, b0, acc[t], 0, 0, 0);
        acc[t] = __builtin_amdgcn_mfma_f32_16x16x32_bf16(a1, b1, acc[t], 0, 0, 0);
    }

    // ---- epilogue in-register ----
    // biases for j = s*16+col
    float bfv[4], bgv[4], bzv[4];
    #pragma unroll
    for (int s = 0; s < 4; ++s) {
        int j = s * 16 + col;
        bfv[s] = bfp[j];
        bgv[s] = bgp[j];
        bzv[s] = (s < 2) ? bzp[j] : bAp[j - 32];
    }

    // s=0,1 (projected features): compute du, accumulate projection partials
    float du01[2][4], uv01[2][4];
    float ar[4], br[4];
    #pragma unroll
    for (int r = 0; r < 4; ++r) { ar[r] = 0.f; br[r] = 0.f; }
    #pragma unroll
    for (int s = 0; s < 2; ++s) {
        #pragma unroll
        for (int r = 0; r < 4; ++r) {
            int nd = n0 + kg * 4 + r;
            float uu = u[(size_t)nd * 64 + s * 16 + col];
            float fpre = acc[s][r] + bfv[s];
            float gpre = acc[4 + s][r] + bgv[s];
            float zpre = acc[8 + s][r] + bzv[s];
            float Fu = softplus_fast(fpre);
            float Gu = softplus_fast(gpre);
            float zv = tanh_fast(zpre);
            float d = -Fu * uu + Gu * zv;
            du01[s][r] = d;
            uv01[s][r] = uu;
            ar[r] = fmaf(d, uu, ar[r]);
            br[r] = fmaf(uu, uu, br[r]);
        }
    }
    // reduce ar/br across the 16-lane col-group (kg preserved)
    #pragma unroll
    for (int off = 1; off < 16; off <<= 1) {
        #pragma unroll
        for (int r = 0; r < 4; ++r) {
            ar[r] += __shfl_xor(ar[r], off);
            br[r] += __shfl_xor(br[r], off);
        }
    }
    float coef[4];
    #pragma unroll
    for (int r = 0; r < 4; ++r) coef[r] = ar[r] * __builtin_amdgcn_rcpf(br[r]);

    // stores: s=0,1 projected; s=2,3 plain (relu branch)
    #pragma unroll
    for (int s = 0; s < 2; ++s) {
        #pragma unroll
        for (int r = 0; r < 4; ++r) {
            int nd = n0 + kg * 4 + r;
            out[(size_t)nd * 64 + s * 16 + col] = du01[s][r] - coef[r] * uv01[s][r];
        }
    }
    #pragma unroll
    for (int s = 2; s < 4; ++s) {
        #pragma unroll
        for (int r = 0; r < 4; ++r) {
            int nd = n0 + kg * 4 + r;
            float uu = u[(size_t)nd * 64 + s * 16 + col];
            float fpre = acc[s][r] + bfv[s];
            float gpre = acc[4 + s][r] + bgv[s];
            float zpre = acc[8 + s][r] + bzv[s];
            float Fu = softplus_fast(fpre);
            float Gu = softplus_fast(gpre);
            float zv = fmaxf(zpre, 0.0f);
            out[(size_t)nd * 64 + s * 16 + col] = -Fu * uu + Gu * zv;
        }
    }
}

extern "C" void kernel_launch(void* const* d_in, const int* in_sizes, int n_in,
                              void* d_out, int out_size, void* d_ws, size_t ws_size,
                              hipStream_t stream) {
    const float* u         = (const float*)d_in[0];
    const float* intensity = (const float*)d_in[1];
    const int*   esrc      = (const int*)d_in[2];
    const int*   edst      = (const int*)d_in[3];
    const float* Wf        = (const float*)d_in[4];
    const float* bf        = (const float*)d_in[5];
    const float* Wg        = (const float*)d_in[6];
    const float* bg        = (const float*)d_in[7];
    const float* Wz        = (const float*)d_in[8];
    const float* bz        = (const float*)d_in[9];
    const float* WA        = (const float*)d_in[10];
    const float* bA        = (const float*)d_in[11];

    int N = in_sizes[0] / 64;
    int E = in_sizes[2];
    int B = (N + RNODES - 1) / RNODES;          // 782
    int M = B * NBLK;                            // 200192
    int nb = (M + 1023) / 1024;                  // 196

    int* cnt       = (int*)d_ws;                 // M
    int* offs      = cnt + M;                    // M
    int* bsum      = offs + M;                   // 1024
    int* binned    = bsum + 1024;                // E
    int* nodestart = binned + E;                 // N
    int* degarr    = nodestart + N;              // N
    unsigned short* xnbr = (unsigned short*)(degarr + N);   // N*32
    unsigned short* wbig = xnbr + (size_t)N * 32;           // 192*64
    unsigned short* ibf  = wbig + 192 * 64;                 // N*32

    cvt_int<<<2048, 256, 0, stream>>>(intensity, ibf, N * 8);
    prep_w<<<48, 256, 0, stream>>>(Wf, Wg, Wz, WA, wbig);
    bin_count<<<NBLK, 1024, 0, stream>>>(edst, cnt, E, B);
    scan_reduce<<<nb, 1024, 0, stream>>>(cnt, bsum, M);
    scan_top<<<1, 1024, 0, stream>>>(bsum, nb);
    scan_final<<<nb, 1024, 0, stream>>>(cnt, bsum, offs, M);
    bin_scatter<<<NBLK, 1024, 0, stream>>>(esrc, edst, offs, binned, E, B);
    node_sort<<<B, 256, 0, stream>>>(binned, offs, nodestart, degarr, E, N, B);
    gather_kernel<<<2048, 256, 0, stream>>>(ibf, binned, nodestart, degarr,
                                            xnbr, N);
    int ntiles = N / 16;
    int nblocks = (ntiles + 3) / 4;
    node_mfma<<<nblocks, 256, 0, stream>>>(u, ibf, xnbr, wbig,
                                           bf, bg, bz, bA, (float*)d_out, N);
}

// Round 11
// 137.781 us; speedup vs baseline: 6.4394x; 1.0493x over previous
//
#include <hip/hip_runtime.h>

// N=100000 nodes, D=64, P=Q=32, E=3200000 edges.
// Pipeline: intensity -> {bf16, fp8-e4m3} copies -> bucket partition (radix
// by dst>>7) -> in-place node sort -> per-node CSR gather on fp8 rows (32B,
// L2-resident table) -> MFMA node kernel, zero-LDS D-fragment epilogue.

#define RLOG 7
#define RNODES 128
#define NBLK 256
#define CAP 6144

typedef __attribute__((ext_vector_type(8))) short short8;
typedef __attribute__((ext_vector_type(4))) float f32x4;
typedef __attribute__((ext_vector_type(2))) float f32x2;

__device__ __forceinline__ unsigned short f2bf(float x) {
    union { float f; unsigned u; } v; v.f = x;
    unsigned r = v.u + 0x7FFF + ((v.u >> 16) & 1);  // RNE
    return (unsigned short)(r >> 16);
}

__device__ __forceinline__ float bf2f(unsigned short b) {
    union { unsigned u; float f; } v; v.u = ((unsigned)b) << 16;
    return v.f;
}

// ---- fp8 pack/unpack: prefer HW cvt (self-consistent encode/decode) ----
#if __has_builtin(__builtin_amdgcn_cvt_pk_fp8_f32) && __has_builtin(__builtin_amdgcn_cvt_pk_f32_fp8)
__device__ __forceinline__ unsigned pack4_fp8(float a, float b, float c, float d) {
    int p = __builtin_amdgcn_cvt_pk_fp8_f32(a, b, 0, false);
    p = __builtin_amdgcn_cvt_pk_fp8_f32(c, d, p, true);
    return (unsigned)p;
}
__device__ __forceinline__ void unpack4_fp8(unsigned w, float& a, float& b, float& c, float& d) {
    f32x2 lo = __builtin_amdgcn_cvt_pk_f32_fp8(w, false);
    f32x2 hi = __builtin_amdgcn_cvt_pk_f32_fp8(w, true);
    a = lo[0]; b = lo[1]; c = hi[0]; d = hi[1];
}
#else
__device__ __forceinline__ unsigned char f2fp8_sw(float x) {
    union { float f; unsigned u; } v; v.f = x;
    unsigned s = (v.u >> 24) & 0x80;
    float ax = fminf(fabsf(x), 448.0f);
    union { float f; unsigned u; } w; w.f = ax;
    int e = (int)((w.u >> 23) & 0xFF) - 127;
    if (e < -6) {
        int mi = (int)(ax * 512.0f + 0.5f);
        if (mi > 7) mi = 7;
        return (unsigned char)(s | mi);
    }
    unsigned mant = (w.u >> 20) & 7;
    unsigned rest = w.u & 0xFFFFF;
    unsigned rnd = (rest > 0x80000u) || (rest == 0x80000u && (mant & 1));
    unsigned enc = ((unsigned)(e + 7) << 3) | mant;
    enc += rnd;
    if (enc > 0x7Eu) enc = 0x7Eu;
    return (unsigned char)(s | enc);
}
__device__ __forceinline__ float fp82f_sw(unsigned char b) {
    unsigned e = (b >> 3) & 0xF, m = b & 7;
    float mag;
    if (e == 0) mag = (float)m * 0.001953125f;
    else {
        union { unsigned u; float f; } v;
        v.u = ((e + 120u) << 23) | (m << 20);
        mag = v.f;
    }
    return (b & 0x80) ? -mag : mag;
}
__device__ __forceinline__ unsigned pack4_fp8(float a, float b, float c, float d) {
    return (unsigned)f2fp8_sw(a) | ((unsigned)f2fp8_sw(b) << 8) |
           ((unsigned)f2fp8_sw(c) << 16) | ((unsigned)f2fp8_sw(d) << 24);
}
__device__ __forceinline__ void unpack4_fp8(unsigned w, float& a, float& b, float& c, float& d) {
    a = fp82f_sw((unsigned char)(w & 0xFF));
    b = fp82f_sw((unsigned char)((w >> 8) & 0xFF));
    c = fp82f_sw((unsigned char)((w >> 16) & 0xFF));
    d = fp82f_sw((unsigned char)((w >> 24) & 0xFF));
}
#endif

__device__ __forceinline__ float softplus_fast(float x) {
    float t = __expf(-fabsf(x));
    return fmaxf(x, 0.0f) + __logf(1.0f + t);
}

__device__ __forceinline__ float tanh_fast(float x) {
    float t = __expf(-2.0f * fabsf(x));
    float m = (1.0f - t) * __builtin_amdgcn_rcpf(1.0f + t);
    return __builtin_copysignf(m, x);
}

__device__ __forceinline__ int chunk_of(int E) {
    return (((E + NBLK - 1) / NBLK) + 3) & ~3;
}

// ---- 0. intensity -> bf16 + fp8 copies
__global__ __launch_bounds__(256) void cvt_int(const float* __restrict__ x,
                                               unsigned short* __restrict__ ybf,
                                               unsigned* __restrict__ yfp8,
                                               int total4) {
    int t0 = blockIdx.x * 256 + threadIdx.x;
    int stride = gridDim.x * 256;
    for (int i = t0; i < total4; i += stride) {
        float4 v = ((const float4*)x)[i];
        ushort4 r;
        r.x = f2bf(v.x); r.y = f2bf(v.y); r.z = f2bf(v.z); r.w = f2bf(v.w);
        ((ushort4*)ybf)[i] = r;
        yfp8[i] = pack4_fp8(v.x, v.y, v.z, v.w);
    }
}

// ---- 1. per-block bucket histogram: cnt[b*NBLK + blk]
__global__ __launch_bounds__(1024) void bin_count(const int* __restrict__ edst,
                                                  int* __restrict__ cnt,
                                                  int E, int B) {
    __shared__ int lcnt[1024];
    int tid = threadIdx.x, blk = blockIdx.x;
    for (int b = tid; b < B; b += 1024) lcnt[b] = 0;
    __syncthreads();
    int chunk = chunk_of(E);
    int start = blk * chunk;
    int end = min(E, start + chunk);
    int v4s = start >> 2, v4e = end >> 2;
    for (int i = v4s + tid; i < v4e; i += 1024) {
        int4 d = ((const int4*)edst)[i];
        atomicAdd(&lcnt[d.x >> RLOG], 1);
        atomicAdd(&lcnt[d.y >> RLOG], 1);
        atomicAdd(&lcnt[d.z >> RLOG], 1);
        atomicAdd(&lcnt[d.w >> RLOG], 1);
    }
    for (int i = (v4e << 2) + tid; i < end; i += 1024)
        atomicAdd(&lcnt[edst[i] >> RLOG], 1);
    __syncthreads();
    for (int b = tid; b < B; b += 1024) cnt[b * NBLK + blk] = lcnt[b];
}

// ---- 2a. per-block partial sums
__global__ __launch_bounds__(1024) void scan_reduce(const int* __restrict__ cnt,
                                                    int* __restrict__ bsum, int M) {
    int idx = blockIdx.x * 1024 + threadIdx.x;
    int v = (idx < M) ? cnt[idx] : 0;
    #pragma unroll
    for (int off = 32; off; off >>= 1) v += __shfl_xor(v, off);
    __shared__ int wtot[16];
    int lane = threadIdx.x & 63, wave = threadIdx.x >> 6;
    if (lane == 0) wtot[wave] = v;
    __syncthreads();
    if (threadIdx.x == 0) {
        int s = 0;
        #pragma unroll
        for (int i = 0; i < 16; ++i) s += wtot[i];
        bsum[blockIdx.x] = s;
    }
}

// ---- 2b. exclusive scan of block sums (single block, nb <= 1024)
__global__ __launch_bounds__(1024) void scan_top(int* __restrict__ bsum, int nb) {
    int t = threadIdx.x;
    int lane = t & 63, wave = t >> 6;
    int v = (t < nb) ? bsum[t] : 0;
    int incl = v;
    #pragma unroll
    for (int off = 1; off < 64; off <<= 1) {
        int w = __shfl_up(incl, off);
        if (lane >= off) incl += w;
    }
    __shared__ int wt[16];
    if (lane == 63) wt[wave] = incl;
    __syncthreads();
    int woff = 0;
    for (int i = 0; i < wave; ++i) woff += wt[i];
    if (t < nb) bsum[t] = woff + incl - v;
}

// ---- 2c. final exclusive scan -> offs
__global__ __launch_bounds__(1024) void scan_final(const int* __restrict__ cnt,
                                                   const int* __restrict__ bsum,
                                                   int* __restrict__ offs, int M) {
    int t = threadIdx.x;
    int idx = blockIdx.x * 1024 + t;
    int lane = t & 63, wave = t >> 6;
    int v = (idx < M) ? cnt[idx] : 0;
    int incl = v;
    #pragma unroll
    for (int off = 1; off < 64; off <<= 1) {
        int w = __shfl_up(incl, off);
        if (lane >= off) incl += w;
    }
    __shared__ int wtot[16];
    if (lane == 63) wtot[wave] = incl;
    __syncthreads();
    int woff = 0;
    for (int i = 0; i < wave; ++i) woff += wtot[i];
    if (idx < M) offs[idx] = bsum[blockIdx.x] + woff + incl - v;
}

// ---- 3. scatter packed entries using LDS cursors (int4 edge loads)
__global__ __launch_bounds__(1024) void bin_scatter(const int* __restrict__ esrc,
                                                    const int* __restrict__ edst,
                                                    const int* __restrict__ offs,
                                                    int* __restrict__ binned,
                                                    int E, int B) {
    __shared__ int lcur[1024];
    int tid = threadIdx.x, blk = blockIdx.x;
    for (int b = tid; b < B; b += 1024) lcur[b] = offs[b * NBLK + blk];
    __syncthreads();
    int chunk = chunk_of(E);
    int start = blk * chunk;
    int end = min(E, start + chunk);
    int v4s = start >> 2, v4e = end >> 2;
    for (int i = v4s + tid; i < v4e; i += 1024) {
        int4 d = ((const int4*)edst)[i];
        int4 s = ((const int4*)esrc)[i];
        int p0 = atomicAdd(&lcur[d.x >> RLOG], 1);
        int p1 = atomicAdd(&lcur[d.y >> RLOG], 1);
        int p2 = atomicAdd(&lcur[d.z >> RLOG], 1);
        int p3 = atomicAdd(&lcur[d.w >> RLOG], 1);
        binned[p0] = ((d.x & (RNODES - 1)) << 17) | s.x;
        binned[p1] = ((d.y & (RNODES - 1)) << 17) | s.y;
        binned[p2] = ((d.z & (RNODES - 1)) << 17) | s.z;
        binned[p3] = ((d.w & (RNODES - 1)) << 17) | s.w;
    }
    for (int i = (v4e << 2) + tid; i < end; i += 1024) {
        int d = edst[i];
        int s = esrc[i];
        int pos = atomicAdd(&lcur[d >> RLOG], 1);
        binned[pos] = ((d & (RNODES - 1)) << 17) | s;
    }
}

// ---- 4. in-place node sort within each bucket
__global__ __launch_bounds__(256) void node_sort(int* __restrict__ binned,
                                                 const int* __restrict__ offs,
                                                 int* __restrict__ nodestart,
                                                 int* __restrict__ degarr,
                                                 int E, int N, int B) {
    __shared__ int sl[CAP];
    __shared__ int c128[RNODES];
    __shared__ int pos[RNODES];
    int tid = threadIdx.x;
    int b = blockIdx.x;
    int start = offs[b * NBLK];
    int end = (b + 1 < B) ? offs[(b + 1) * NBLK] : E;
    int m = min(end - start, CAP);

    for (int i = tid; i < m; i += 256) sl[i] = binned[start + i];
    if (tid < RNODES) c128[tid] = 0;
    __syncthreads();
    for (int i = tid; i < m; i += 256) atomicAdd(&c128[sl[i] >> 17], 1);
    __syncthreads();

    int x = 0, incl = 0;
    if (tid < RNODES) { x = c128[tid]; incl = x; }
    #pragma unroll
    for (int off = 1; off < RNODES; off <<= 1) {
        int y = 0;
        if (tid < RNODES && tid >= off) y = c128[tid - off];
        __syncthreads();
        if (tid < RNODES) { incl += y; c128[tid] = incl; }
        __syncthreads();
    }
    if (tid < RNODES) {
        int excl = incl - x;
        pos[tid] = excl;
        int node = b * RNODES + tid;
        if (node < N) {
            nodestart[node] = start + excl;
            degarr[node] = x;
        }
    }
    __syncthreads();
    for (int i = tid; i < m; i += 256) {
        int e = sl[i];
        int p = atomicAdd(&pos[e >> 17], 1);
        binned[start + p] = e & 131071;
    }
}

// ---- 5. gather on fp8 rows (32B, L2-resident): 8 lanes/edge, unroll 4
__global__ __launch_bounds__(256) void gather_kernel(
    const unsigned* __restrict__ ifp8, const int* __restrict__ binned,
    const int* __restrict__ nodestart, const int* __restrict__ degarr,
    unsigned short* __restrict__ xnbr, int N) {
    int lane = threadIdx.x & 63;
    int wave = threadIdx.x >> 6;
    int gid = lane >> 3;       // 8 groups of 8 lanes
    int fl = lane & 7;         // uint index within the 32-feature fp8 row
    int gwave = blockIdx.x * 4 + wave;
    int wstride = gridDim.x * 4;
    for (int n = gwave; n < N; n += wstride) {
        int st = nodestart[n];
        int dg = degarr[n];
        float a0 = 0.f, a1 = 0.f, a2 = 0.f, a3 = 0.f;
        int j = gid;
        for (; j + 24 < dg; j += 32) {
            int s0 = binned[st + j];
            int s1 = binned[st + j + 8];
            int s2 = binned[st + j + 16];
            int s3 = binned[st + j + 24];
            unsigned w0 = ifp8[(size_t)s0 * 8 + fl];
            unsigned w1 = ifp8[(size_t)s1 * 8 + fl];
            unsigned w2 = ifp8[(size_t)s2 * 8 + fl];
            unsigned w3 = ifp8[(size_t)s3 * 8 + fl];
            float x0, x1, x2, x3;
            unpack4_fp8(w0, x0, x1, x2, x3);
            a0 += x0; a1 += x1; a2 += x2; a3 += x3;
            unpack4_fp8(w1, x0, x1, x2, x3);
            a0 += x0; a1 += x1; a2 += x2; a3 += x3;
            unpack4_fp8(w2, x0, x1, x2, x3);
            a0 += x0; a1 += x1; a2 += x2; a3 += x3;
            unpack4_fp8(w3, x0, x1, x2, x3);
            a0 += x0; a1 += x1; a2 += x2; a3 += x3;
        }
        for (; j < dg; j += 8) {
            int s0 = binned[st + j];
            unsigned w0 = ifp8[(size_t)s0 * 8 + fl];
            float x0, x1, x2, x3;
            unpack4_fp8(w0, x0, x1, x2, x3);
            a0 += x0; a1 += x1; a2 += x2; a3 += x3;
        }
        #pragma unroll
        for (int off = 8; off < 64; off <<= 1) {
            a0 += __shfl_xor(a0, off);
            a1 += __shfl_xor(a1, off);
            a2 += __shfl_xor(a2, off);
            a3 += __shfl_xor(a3, off);
        }
        if (lane < 8) {
            float inv = (dg > 0) ? 1.0f / (float)dg : 0.0f;
            ushort4 r;
            r.x = f2bf(a0 * inv); r.y = f2bf(a1 * inv);
            r.z = f2bf(a2 * inv); r.w = f2bf(a3 * inv);
            ((ushort4*)xnbr)[(size_t)n * 8 + fl] = r;
        }
    }
}

// ---- 6. build stacked bf16 weight matrix Wbig[192][64]
__global__ __launch_bounds__(256) void prep_w(const float* __restrict__ Wf,
                                              const float* __restrict__ Wg,
                                              const float* __restrict__ Wz,
                                              const float* __restrict__ WA,
                                              unsigned short* __restrict__ wbig) {
    int idx = blockIdx.x * 256 + threadIdx.x;
    if (idx >= 192 * 64) return;
    int r = idx >> 6, k = idx & 63;
    float v = (r < 64)  ? Wf[r * 64 + k]
            : (r < 128) ? Wg[(r - 64) * 64 + k]
            : (r < 160) ? Wz[(r - 128) * 64 + k]
                        : WA[(r - 160) * 64 + k];
    wbig[idx] = f2bf(v);
}

// ---- 7. MFMA node kernel, zero-LDS epilogue in D-fragment layout.
__global__ __launch_bounds__(256, 4) void node_mfma(
    const float* __restrict__ u,
    const unsigned short* __restrict__ ibf,
    const unsigned short* __restrict__ xnbr,
    const unsigned short* __restrict__ wbig,
    const float* __restrict__ bfp, const float* __restrict__ bgp,
    const float* __restrict__ bzp, const float* __restrict__ bAp,
    float* __restrict__ out, int N) {
    int tid = threadIdx.x;
    int lane = tid & 63;
    int wave = tid >> 6;
    int tile = blockIdx.x * 4 + wave;
    int ntiles = N >> 4;
    if (tile >= ntiles) return;

    int col = lane & 15;
    int kg = lane >> 4;
    int n0 = tile * 16;
    int node = n0 + col;

    const float* ub = u + (size_t)node * 64 + kg * 8;
    float4 u0 = *(const float4*)(ub);
    float4 u1 = *(const float4*)(ub + 4);
    float4 u2 = *(const float4*)(ub + 32);
    float4 u3 = *(const float4*)(ub + 36);
    short8 au0, au1;
    au0[0]=(short)f2bf(u0.x); au0[1]=(short)f2bf(u0.y); au0[2]=(short)f2bf(u0.z); au0[3]=(short)f2bf(u0.w);
    au0[4]=(short)f2bf(u1.x); au0[5]=(short)f2bf(u1.y); au0[6]=(short)f2bf(u1.z); au0[7]=(short)f2bf(u1.w);
    au1[0]=(short)f2bf(u2.x); au1[1]=(short)f2bf(u2.y); au1[2]=(short)f2bf(u2.z); au1[3]=(short)f2bf(u2.w);
    au1[4]=(short)f2bf(u3.x); au1[5]=(short)f2bf(u3.y); au1[6]=(short)f2bf(u3.z); au1[7]=(short)f2bf(u3.w);
    short8 ax0 = *(const short8*)(ibf  + (size_t)node * 32 + kg * 8);
    short8 ax1 = *(const short8*)(xnbr + (size_t)node * 32 + kg * 8);

    const short8* wb = (const short8*)wbig;
    f32x4 acc[12];
    #pragma unroll
    for (int t = 0; t < 12; ++t) acc[t] = (f32x4){0.f, 0.f, 0.f, 0.f};
    #pragma unroll
    for (int t = 0; t < 12; ++t) {
        short8 a0 = (t < 10) ? au0 : ax0;
        short8 a1 = (t < 10) ? au1 : ax1;
        short8 b0 = wb[(t * 16 + col) * 8 + kg];
        short8 b1 = wb[(t * 16 + col) * 8 + 4 + kg];
        acc[t] = __builtin_amdgcn_mfma_f32_16x16x32_bf16(a0, b0, acc[t], 0, 0, 0);
        acc[t] = __builtin_amdgcn_mfma_f32_16x16x32_bf16(a1, b1, acc[t], 0, 0, 0);
    }

    float bfv[4], bgv[4], bzv[4];
    #pragma unroll
    for (int s = 0; s < 4; ++s) {
        int j = s * 16 + col;
        bfv[s] = bfp[j];
        bgv[s] = bgp[j];
        bzv[s] = (s < 2) ? bzp[j] : bAp[j - 32];
    }

    float du01[2][4], uv01[2][4];
    float ar[4], br[4];
    #pragma unroll
    for (int r = 0; r < 4; ++r) { ar[r] = 0.f; br[r] = 0.f; }
    #pragma unroll
    for (int s = 0; s < 2; ++s) {
        #pragma unroll
        for (int r = 0; r < 4; ++r) {
            int nd = n0 + kg * 4 + r;
            float uu = u[(size_t)nd * 64 + s * 16 + col];
            float fpre = acc[s][r] + bfv[s];
            float gpre = acc[4 + s][r] + bgv[s];
            float zpre = acc[8 + s][r] + bzv[s];
            float Fu = softplus_fast(fpre);
            float Gu = softplus_fast(gpre);
            float zv = tanh_fast(zpre);
            float d = -Fu * uu + Gu * zv;
            du01[s][r] = d;
            uv01[s][r] = uu;
            ar[r] = fmaf(d, uu, ar[r]);
            br[r] = fmaf(uu, uu, br[r]);
        }
    }
    #pragma unroll
    for (int off = 1; off < 16; off <<= 1) {
        #pragma unroll
        for (int r = 0; r < 4; ++r) {
            ar[r] += __shfl_xor(ar[r], off);
            br[r] += __shfl_xor(br[r], off);
        }
    }
    float coef[4];
    #pragma unroll
    for (int r = 0; r < 4; ++r) coef[r] = ar[r] * __builtin_amdgcn_rcpf(br[r]);

    #pragma unroll
    for (int s = 0; s < 2; ++s) {
        #pragma unroll
        for (int r = 0; r < 4; ++r) {
            int nd = n0 + kg * 4 + r;
            out[(size_t)nd * 64 + s * 16 + col] = du01[s][r] - coef[r] * uv01[s][r];
        }
    }
    #pragma unroll
    for (int s = 2; s < 4; ++s) {
        #pragma unroll
        for (int r = 0; r < 4; ++r) {
            int nd = n0 + kg * 4 + r;
            float uu = u[(size_t)nd * 64 + s * 16 + col];
            float fpre = acc[s][r] + bfv[s];
            float gpre = acc[4 + s][r] + bgv[s];
            float zpre = acc[8 + s][r] + bzv[s];
            float Fu = softplus_fast(fpre);
            float Gu = softplus_fast(gpre);
            float zv = fmaxf(zpre, 0.0f);
            out[(size_t)nd * 64 + s * 16 + col] = -Fu * uu + Gu * zv;
        }
    }
}

extern "C" void kernel_launch(void* const* d_in, const int* in_sizes, int n_in,
                              void* d_out, int out_size, void* d_ws, size_t ws_size,
                              hipStream_t stream) {
    const float* u         = (const float*)d_in[0];
    const float* intensity = (const float*)d_in[1];
    const int*   esrc      = (const int*)d_in[2];
    const int*   edst      = (const int*)d_in[3];
    const float* Wf        = (const float*)d_in[4];
    const float* bf        = (const float*)d_in[5];
    const float* Wg        = (const float*)d_in[6];
    const float* bg        = (const float*)d_in[7];
    const float* Wz        = (const float*)d_in[8];
    const float* bz        = (const float*)d_in[9];
    const float* WA        = (const float*)d_in[10];
    const float* bA        = (const float*)d_in[11];

    int N = in_sizes[0] / 64;
    int E = in_sizes[2];
    int B = (N + RNODES - 1) / RNODES;          // 782
    int M = B * NBLK;                            // 200192
    int nb = (M + 1023) / 1024;                  // 196

    int* cnt       = (int*)d_ws;                 // M
    int* offs      = cnt + M;                    // M
    int* bsum      = offs + M;                   // 1024
    int* binned    = bsum + 1024;                // E
    int* nodestart = binned + E;                 // N
    int* degarr    = nodestart + N;              // N
    unsigned short* xnbr = (unsigned short*)(degarr + N);   // N*32
    unsigned short* wbig = xnbr + (size_t)N * 32;           // 192*64
    unsigned short* ibf  = wbig + 192 * 64;                 // N*32
    unsigned* ifp8 = (unsigned*)(ibf + (size_t)N * 32);     // N*8 uints

    cvt_int<<<2048, 256, 0, stream>>>(intensity, ibf, ifp8, N * 8);
    prep_w<<<48, 256, 0, stream>>>(Wf, Wg, Wz, WA, wbig);
    bin_count<<<NBLK, 1024, 0, stream>>>(edst, cnt, E, B);
    scan_reduce<<<nb, 1024, 0, stream>>>(cnt, bsum, M);
    scan_top<<<1, 1024, 0, stream>>>(bsum, nb);
    scan_final<<<nb, 1024, 0, stream>>>(cnt, bsum, offs, M);
    bin_scatter<<<NBLK, 1024, 0, stream>>>(esrc, edst, offs, binned, E, B);
    node_sort<<<B, 256, 0, stream>>>(binned, offs, nodestart, degarr, E, N, B);
    gather_kernel<<<2048, 256, 0, stream>>>(ifp8, binned, nodestart, degarr,
                                            xnbr, N);
    int ntiles = N / 16;
    int nblocks = (ntiles + 3) / 4;
    node_mfma<<<nblocks, 256, 0, stream>>>(u, ibf, xnbr, wbig,
                                           bf, bg, bz, bA, (float*)d_out, N);
}